// Round 13
// baseline (422.240 us; speedup 1.0000x reference)
//
#include <hip/hip_runtime.h>
#include <hip/hip_bf16.h>
#include <math.h>

#define NTOK   16384
#define DM     768
#define DF     3072
#define NEXP   4

// prep kernel fat-grid sections (routing + X cvt + W1 transpose;
// W2 transpose runs as tail blocks of gemm1, overlapped with compute)
#define RBLKS  64                      // routing: 256 tokens per block
#define XBLKS  768                     // X cvt: 8 units of 2048 elems each
#define WBLKS  288                     // W1 transpose: 8 tiles of 64x64 each
#define PREP_BLKS (RBLKS + XBLKS + WBLKS)   // 1120
#define W2BLKS 288                     // W2 transpose tail blocks inside gemm1

typedef short bf16x8 __attribute__((ext_vector_type(8)));
typedef float f32x4  __attribute__((ext_vector_type(4)));

// ---------------- workspace layout (bytes) ----------------
#define WS_CNT    0u
#define WS_BASES  256u                        // (unused slot, kept for layout stability)
#define WS_POS    512u                        // NTOK ints            = 65536
#define WS_LIST   (512u + 65536u)             // NEXP*NTOK ints       = 262144
#define WS_XB     (WS_LIST + 262144u)         // NTOK*DM bf16         = 25165824
#define WS_W1T    (WS_XB + 25165824u)         // 4*DF*DM bf16         = 18874368
#define WS_W2T    (WS_W1T + 18874368u)        // 4*DM*DF bf16         = 18874368
#define WS_H1     (WS_W2T + 18874368u)        // NTOK*DF bf16         = 100663296
#define WS_H2     (WS_H1 + 100663296u)        // NTOK*DM bf16         = 25165824
#define WS_END    (WS_H2 + 25165824u)

// ---------------- bf16 helpers (manual, RNE) ----------------
__device__ __forceinline__ ushort f2bf(float f) {
    unsigned int v; __builtin_memcpy(&v, &f, 4);
    v = v + 0x7fffu + ((v >> 16) & 1u);
    return (ushort)(v >> 16);
}
__device__ __forceinline__ float bf2f(ushort u) {
    unsigned int v = ((unsigned int)u) << 16;
    float f; __builtin_memcpy(&f, &v, 4); return f;
}

// fast gelu: x * sigmoid(1.5957691(x + 0.044715 x^3)); exp2-based, ~1e-3 abs err
__device__ __forceinline__ float fast_gelu(float v) {
    float y = v + 0.044715f * v * v * v;
    float e = __builtin_amdgcn_exp2f(-2.3022082f * y);
    return v * __builtin_amdgcn_rcpf(1.0f + e);
}

// async global->LDS, 16B per lane. LDS dest must be uniform_base + lane*16.
typedef __attribute__((address_space(1))) const void gvoid_t;
typedef __attribute__((address_space(3))) void lvoid_t;
__device__ __forceinline__ void cp16(const void* g, void* l) {
    __builtin_amdgcn_global_load_lds((gvoid_t*)g, (lvoid_t*)l, 16, 0, 0);
}

// bijective chunked XCD remap over T active blocks (m204 formula)
__device__ __forceinline__ int xcd_remap(int id, int T) {
    const int q = T >> 3, r = T & 7;
    const int x = id & 7, j = id >> 3;
    return (x < r ? x * (q + 1) : r * (q + 1) + (x - r) * q) + j;
}

// ---------------- prep: parallel routing + X cvt + W1 transpose ----------------
__global__ __launch_bounds__(256) void prep_kernel(
    const int* __restrict__ type_seq, const float* __restrict__ X,
    const float* __restrict__ W1,
    int* __restrict__ cnt,
    int* __restrict__ pos_of, int* __restrict__ list,
    ushort* __restrict__ Xb, ushort* __restrict__ W1t) {
    __shared__ ushort tbuf[2][64 * 72];
    __shared__ int lcnt[NEXP];
    __shared__ int lbase[NEXP];
    const int tid = threadIdx.x;
    const int bid = blockIdx.x;

    if (bid < RBLKS) {
        if (tid < NEXP) lcnt[tid] = 0;
        __syncthreads();
        const int lane = tid & 63;
        const int t = bid * 256 + tid;
        const int k = type_seq[t];
        int my_e = -1, my_p = 0;
#pragma unroll
        for (int e = 0; e < NEXP; ++e) {
            unsigned long long m = __ballot(k == e + 1);
            int total = __popcll(m);
            int b = 0;
            if (lane == 0 && total) b = atomicAdd(&lcnt[e], total);
            b = __shfl(b, 0, 64);
            if (k == e + 1) {
                my_e = e;
                my_p = b + __popcll(m & ((1ull << lane) - 1ull));
            }
        }
        __syncthreads();
        if (tid < NEXP && lcnt[tid] > 0)
            lbase[tid] = atomicAdd(&cnt[tid], lcnt[tid]);   // global, device-scope
        __syncthreads();
        if (my_e >= 0) {
            int gp = lbase[my_e] + my_p;
            list[my_e * NTOK + gp] = t;
            pos_of[t] = gp;
        }
        return;
    }

    int id = bid - RBLKS;
    if (id < XBLKS) {
        // ---- X fp32 -> bf16, 8 batched units per block ----
        size_t ibase = ((size_t)id * 8 * 256 + tid) * 8;
        float4 va[8], vb[8];
#pragma unroll
        for (int k = 0; k < 8; ++k) {
            va[k] = *(const float4*)(X + ibase + (size_t)k * 2048);
            vb[k] = *(const float4*)(X + ibase + (size_t)k * 2048 + 4);
        }
#pragma unroll
        for (int k = 0; k < 8; ++k) {
            ushort tmp[8];
            tmp[0] = f2bf(va[k].x); tmp[1] = f2bf(va[k].y);
            tmp[2] = f2bf(va[k].z); tmp[3] = f2bf(va[k].w);
            tmp[4] = f2bf(vb[k].x); tmp[5] = f2bf(vb[k].y);
            tmp[6] = f2bf(vb[k].z); tmp[7] = f2bf(vb[k].w);
            *(uint4*)(Xb + ibase + (size_t)k * 2048) = *(uint4*)tmp;
        }
        return;
    }
    id -= XBLKS;
    {
        // ---- W1 [z][768][3072] -> W1t [z][3072][768], 8 pipelined tiles ----
        const int lr = tid >> 3;            // 0..31
        const int lc = (tid & 7) * 8;       // 0,8,..,56
        float4 v[2][2];
        const int base_tt = id * 8;
        auto LOADT = [&](int tt) {
            int z = tt / 576, rr = tt % 576, bx = rr % 48, by = rr / 48;
            const float* s0 = W1 + (size_t)z * DM * DF + (size_t)(by * 64 + lr) * DF + bx * 64 + lc;
            v[0][0] = *(const float4*)s0;       v[0][1] = *(const float4*)(s0 + 4);
            const float* s1 = s0 + (size_t)32 * DF;
            v[1][0] = *(const float4*)s1;       v[1][1] = *(const float4*)(s1 + 4);
        };
        LOADT(base_tt);
#pragma unroll 1
        for (int k = 0; k < 8; ++k) {
            ushort* tb = &tbuf[k & 1][0];
#pragma unroll
            for (int q = 0; q < 2; ++q) {
                int r = lr + q * 32;
                ushort tmp[8];
                tmp[0] = f2bf(v[q][0].x); tmp[1] = f2bf(v[q][0].y);
                tmp[2] = f2bf(v[q][0].z); tmp[3] = f2bf(v[q][0].w);
                tmp[4] = f2bf(v[q][1].x); tmp[5] = f2bf(v[q][1].y);
                tmp[6] = f2bf(v[q][1].z); tmp[7] = f2bf(v[q][1].w);
                int sw = (((lc >> 3) ^ ((r >> 3) & 7)) << 3);
                *(uint4*)&tb[r * 72 + sw] = *(uint4*)tmp;
            }
            if (k < 7) LOADT(base_tt + k + 1);
            __syncthreads();
            int tt = base_tt + k;
            int z = tt / 576, rr = tt % 576, bx = rr % 48, by = rr / 48;
#pragma unroll
            for (int q = 0; q < 2; ++q) {
                int r = lr + q * 32;
                ushort tmp[8];
#pragma unroll
                for (int j = 0; j < 8; ++j)
                    tmp[j] = tb[(lc + j) * 72 +
                                ((((r >> 3) & 7) ^ (((lc + j) >> 3) & 7)) << 3) + (r & 7)];
                *(uint4*)(W1t + (size_t)z * DM * DF + (size_t)(bx * 64 + r) * DM + by * 64 + lc) = *(uint4*)tmp;
            }
        }
    }
}

// =====================================================================
// gemm1 (verified R9/R12 best, frozen): tile 128x128, 24 n-blocks, 512
// thr = 8 waves of 64x32. TRIPLE-buffered LDS, depth-2 counted vmcnt(2).
// W2-transpose tail blocks overlapped. Inline panel scan (128-row).
// =====================================================================
__global__ __launch_bounds__(512, 4) void gemm1_kernel(
    const ushort* __restrict__ Xb, const ushort* __restrict__ W1t,
    const float* __restrict__ b1, const int* __restrict__ cnt,
    const int* __restrict__ list, ushort* __restrict__ h1,
    const float* __restrict__ W2, ushort* __restrict__ W2t) {
    __shared__ __align__(16) short As[3][4096];
    __shared__ __align__(16) short Bs[3][4096];
    const int tid = threadIdx.x;

    const int c0 = cnt[0], c1 = cnt[1], c2 = cnt[2], c3 = cnt[3];
    const int p0 = (c0 + 127) >> 7, p1 = (c1 + 127) >> 7, p2 = (c2 + 127) >> 7;
    const int mb = p0 + p1 + p2 + ((c3 + 127) >> 7);
    const int T = mb * 24;
    int id = blockIdx.y * 24 + blockIdx.x;

    if (id >= T) {
        // ---------- W2 transpose tail blocks ----------
        int wid = id - T;
        if (wid >= W2BLKS) return;
        ushort* tb = (ushort*)&As[0][0];        // 9216 B scratch (spans As[0..1])
        const int lr = tid >> 3;                // 0..63
        const int lc = (tid & 7) * 8;           // 0..56
#pragma unroll 1
        for (int k = 0; k < 8; ++k) {
            int tt = wid * 8 + k;
            int zz = tt / 576, rr = tt % 576, bx = rr % 12, by = rr / 12;
            size_t mbase = (size_t)zz * DM * DF;
            const float* s = W2 + mbase + (size_t)(by * 64 + lr) * DM + bx * 64 + lc;
            float4 v0 = *(const float4*)s;
            float4 v1 = *(const float4*)(s + 4);
            ushort tmp[8];
            tmp[0] = f2bf(v0.x); tmp[1] = f2bf(v0.y); tmp[2] = f2bf(v0.z); tmp[3] = f2bf(v0.w);
            tmp[4] = f2bf(v1.x); tmp[5] = f2bf(v1.y); tmp[6] = f2bf(v1.z); tmp[7] = f2bf(v1.w);
            int sw = (((lc >> 3) ^ ((lr >> 3) & 7)) << 3);
            __syncthreads();                    // protect prior iter's reads
            *(uint4*)&tb[lr * 72 + sw] = *(uint4*)tmp;
            __syncthreads();
            ushort o[8];
#pragma unroll
            for (int j = 0; j < 8; ++j)
                o[j] = tb[(lc + j) * 72 +
                          ((((lr >> 3) & 7) ^ (((lc + j) >> 3) & 7)) << 3) + (lr & 7)];
            *(uint4*)(W2t + mbase + (size_t)(bx * 64 + lr) * DF + by * 64 + lc) = *(uint4*)o;
        }
        return;
    }

    id = xcd_remap(id, T);
    const int y = id / 24;
    const int n0 = (id % 24) * 128;
    const int q1 = p0, q2 = p0 + p1, q3 = p0 + p1 + p2;
    const int e = (y >= q1) + (y >= q2) + (y >= q3);
    const int mstart = (e > 0) * p0 + (e > 1) * p1 + (e > 2) * p2;
    const int m0 = (y - mstart) << 7;
    const int count = (e == 0) ? c0 : ((e == 1) ? c1 : ((e == 2) ? c2 : c3));
    const int base = (e > 0) * c0 + (e > 1) * c1 + (e > 2) * c2;
    const int NK = DM / 32;   // 24

    const int wave = tid >> 6, lane = tid & 63;
    const int wm = (wave & 1) * 64, wn = (wave >> 1) * 32;
    const int lrow = lane & 15;
    const int qg = lane >> 4;

    int r0 = min(m0 + (tid >> 2), count - 1);
    int t0 = list[e * NTOK + r0];
    const int qsrc = ((tid & 3) ^ ((tid >> 3) & 3)) * 8;   // source k-quad pre-swizzle
    const ushort* a0 = Xb + (size_t)t0 * DM + qsrc;
    const ushort* Wb = W1t + (size_t)e * DF * DM;
    const ushort* bp0 = Wb + (size_t)(n0 + (tid >> 2)) * DM + qsrc;

    int aOff[4], bOff[2];
#pragma unroll
    for (int i = 0; i < 4; ++i) {
        int ra = wm + i * 16 + lrow;
        aOff[i] = ra * 32 + (qg ^ ((ra >> 1) & 3)) * 8;
    }
#pragma unroll
    for (int j = 0; j < 2; ++j) {
        int rb = wn + j * 16 + lrow;
        bOff[j] = rb * 32 + (qg ^ ((rb >> 1) & 3)) * 8;
    }

    f32x4 z = {0.f, 0.f, 0.f, 0.f};
    f32x4 acc[4][2];
#pragma unroll
    for (int i = 0; i < 4; ++i)
#pragma unroll
        for (int j = 0; j < 2; ++j) acc[i][j] = z;

    auto STAGE = [&](int wb) {
        cp16(a0, &As[0][0] + wb * 4096 + tid * 8);
        cp16(bp0, &Bs[0][0] + wb * 4096 + tid * 8);
        a0 += 32; bp0 += 32;
    };

    STAGE(0); STAGE(1);                         // depth-2 prologue, 4 cp16 in flight
    int rb = 0;
    for (int ks = 0; ks < NK; ++ks) {
        __builtin_amdgcn_sched_barrier(0);
        if (ks + 1 < NK) { asm volatile("s_waitcnt vmcnt(2)" ::: "memory"); }
        else             { asm volatile("s_waitcnt vmcnt(0)" ::: "memory"); }
        __builtin_amdgcn_s_barrier();
        __builtin_amdgcn_sched_barrier(0);
        if (ks + 2 < NK) {
            int wb = rb - 1; if (wb < 0) wb += 3;   // (ks+2)%3
            STAGE(wb);
        }
        const short* Ab = &As[0][0] + rb * 4096;
        const short* Bb = &Bs[0][0] + rb * 4096;
        bf16x8 av[4], bv[2];
#pragma unroll
        for (int i = 0; i < 4; ++i) av[i] = *(const bf16x8*)(Ab + aOff[i]);
#pragma unroll
        for (int j = 0; j < 2; ++j) bv[j] = *(const bf16x8*)(Bb + bOff[j]);
#pragma unroll
        for (int i = 0; i < 4; ++i)
#pragma unroll
            for (int j = 0; j < 2; ++j)
                acc[i][j] = __builtin_amdgcn_mfma_f32_16x16x32_bf16(av[i], bv[j], acc[i][j], 0, 0, 0);
        rb = (rb + 1 == 3) ? 0 : rb + 1;
    }

    float bias[2];
#pragma unroll
    for (int nt = 0; nt < 2; ++nt)
        bias[nt] = b1[e * DF + n0 + wn + nt * 16 + lrow];
#pragma unroll
    for (int mt = 0; mt < 4; ++mt) {
        int gm = m0 + wm + mt * 16 + (lane >> 4) * 4;
#pragma unroll
        for (int nt = 0; nt < 2; ++nt) {
            int gn = n0 + wn + nt * 16 + lrow;
#pragma unroll
            for (int r = 0; r < 4; ++r) {
                int i = gm + r;
                if (i < count) {
                    float v = acc[mt][nt][r] + bias[nt];
                    h1[(size_t)(base + i) * DF + gn] = f2bf(fast_gelu(v));
                }
            }
        }
    }
}

// =====================================================================
// gemm2 (NEW deep-pipelined): tile 256x128, BK=64, 512 thr = 8 waves
// (4M x 2N) each owning 64x64. LDS 3 x (A 32K + B 16K) = 144 KiB ->
// 1 blk/CU. Per K-tile: issue 6 cp16 for tile k+2 -> counted
// s_waitcnt vmcnt(12) (k's loads landed; 12 stay in flight, never
// drained mid-loop) -> s_barrier -> 2 phases, each {ds_read frags,
// lgkmcnt(0)+sched_barrier (rule #18), setprio(1), 16 MFMA,
// setprio(0), s_barrier}. WAR-safe: buffer (k+3)%3 overwrite loads
// issue only after the barrier following its last read. 8-quad XOR
// swizzle key=row&7 (pre-swizzled source; 2 lanes/bank = free).
// 256-row panel scan inline. XCD remap.
// =====================================================================
__global__ __launch_bounds__(512, 2) void gemm2_kernel(
    const ushort* __restrict__ h1, const ushort* __restrict__ W2t,
    const float* __restrict__ b2, const int* __restrict__ cnt,
    ushort* __restrict__ h2) {
    const int c0 = cnt[0], c1 = cnt[1], c2 = cnt[2], c3 = cnt[3];
    const int p0 = (c0 + 255) >> 8, p1 = (c1 + 255) >> 8, p2 = (c2 + 255) >> 8;
    const int mb = p0 + p1 + p2 + ((c3 + 255) >> 8);
    const int T = mb * 6;
    int id = blockIdx.y * 6 + blockIdx.x;
    if (id >= T) return;
    id = xcd_remap(id, T);
    const int y = id / 6;
    const int n0 = (id % 6) * 128;
    const int q1 = p0, q2 = p0 + p1, q3 = p0 + p1 + p2;
    const int e = (y >= q1) + (y >= q2) + (y >= q3);
    const int mstart = (e > 0) * p0 + (e > 1) * p1 + (e > 2) * p2;
    const int m0 = (y - mstart) << 8;
    const int count = (e == 0) ? c0 : ((e == 1) ? c1 : ((e == 2) ? c2 : c3));
    const int base = (e > 0) * c0 + (e > 1) * c1 + (e > 2) * c2;
    const int NK = DF / 64;   // 48 K-tiles

    __shared__ __align__(16) short As[3][16384];   // 256 rows x 64
    __shared__ __align__(16) short Bs[3][8192];    // 128 rows x 64

    const int tid = threadIdx.x;
    const int wave = tid >> 6, lane = tid & 63;
    const int wr = wave >> 1, wc = wave & 1;        // 4M x 2N
    const int lrow = lane & 15;
    const int qg = lane >> 4;

    // ---- staging setup: thread stages rows srow+64s, quad tid&7 (pre-swizzled) ----
    const int srow = tid >> 3;                      // 0..63
    const int qsrc = ((tid & 7) ^ (srow & 7)) * 8;  // source k-quad pre-swizzle
    const ushort* aP[4];
#pragma unroll
    for (int s = 0; s < 4; ++s) {
        int r = min(m0 + srow + s * 64, count - 1);
        aP[s] = h1 + (size_t)(base + r) * DF + qsrc;
    }
    const ushort* Wb = W2t + (size_t)e * DM * DF;
    const ushort* bP[2];
#pragma unroll
    for (int s = 0; s < 2; ++s)
        bP[s] = Wb + (size_t)(n0 + srow + s * 64) * DF + qsrc;

    // ---- fragment read offsets (kh=0; kh=1 = ^32 shorts) ----
    int aOff[4], bOff[4];
#pragma unroll
    for (int i = 0; i < 4; ++i) {
        int ra = wr * 64 + i * 16 + lrow;
        aOff[i] = ra * 64 + (qg ^ (ra & 7)) * 8;
        int rb = wc * 64 + i * 16 + lrow;
        bOff[i] = rb * 64 + (qg ^ (rb & 7)) * 8;
    }

    f32x4 z = {0.f, 0.f, 0.f, 0.f};
    f32x4 acc[4][4];
#pragma unroll
    for (int i = 0; i < 4; ++i)
#pragma unroll
        for (int j = 0; j < 4; ++j) acc[i][j] = z;

    auto STAGE = [&](int buf) {
        short* aD = &As[buf][0] + tid * 8;
        short* bD = &Bs[buf][0] + tid * 8;
#pragma unroll
        for (int s = 0; s < 4; ++s) { cp16(aP[s], aD + s * 4096); aP[s] += 64; }
#pragma unroll
        for (int s = 0; s < 2; ++s) { cp16(bP[s], bD + s * 4096); bP[s] += 64; }
    };

    STAGE(0); STAGE(1);                         // 12 cp16 in flight
    int rb = 0, sb = 2;
    for (int kt = 0; kt < NK; ++kt) {
        if (kt + 2 < NK) {
            STAGE(sb);                          // tile kt+2 -> buf (kt+2)%3
            sb = (sb + 1 == 3) ? 0 : sb + 1;
        }
        __builtin_amdgcn_sched_barrier(0);
        if (kt + 2 < NK)      { asm volatile("s_waitcnt vmcnt(12)" ::: "memory"); }
        else if (kt + 1 < NK) { asm volatile("s_waitcnt vmcnt(6)" ::: "memory"); }
        else                  { asm volatile("s_waitcnt vmcnt(0)" ::: "memory"); }
        __builtin_amdgcn_s_barrier();           // tile kt fully in LDS
        __builtin_amdgcn_sched_barrier(0);

        const short* Ab = &As[rb][0];
        const short* Bb = &Bs[rb][0];

        // ---- phase 0: m-frags 0,1 x all n x kh0,1 (16 MFMA) ----
        bf16x8 av0[2][2], bv[4][2];
#pragma unroll
        for (int i = 0; i < 2; ++i) {
            av0[i][0] = *(const bf16x8*)(Ab + aOff[i]);
            av0[i][1] = *(const bf16x8*)(Ab + (aOff[i] ^ 32));
        }
#pragma unroll
        for (int j = 0; j < 4; ++j) {
            bv[j][0] = *(const bf16x8*)(Bb + bOff[j]);
            bv[j][1] = *(const bf16x8*)(Bb + (bOff[j] ^ 32));
        }
        asm volatile("s_waitcnt lgkmcnt(0)" ::: "memory");
        __builtin_amdgcn_sched_barrier(0);
        __builtin_amdgcn_s_setprio(1);
#pragma unroll
        for (int i = 0; i < 2; ++i)
#pragma unroll
            for (int j = 0; j < 4; ++j) {
                acc[i][j] = __builtin_amdgcn_mfma_f32_16x16x32_bf16(av0[i][0], bv[j][0], acc[i][j], 0, 0, 0);
                acc[i][j] = __builtin_amdgcn_mfma_f32_16x16x32_bf16(av0[i][1], bv[j][1], acc[i][j], 0, 0, 0);
            }
        __builtin_amdgcn_s_setprio(0);
        __builtin_amdgcn_s_barrier();

        // ---- phase 1: m-frags 2,3 x all n x kh0,1 (16 MFMA; B reused in regs) ----
        bf16x8 av1[2][2];
#pragma unroll
        for (int i = 0; i < 2; ++i) {
            av1[i][0] = *(const bf16x8*)(Ab + aOff[2 + i]);
            av1[i][1] = *(const bf16x8*)(Ab + (aOff[2 + i] ^ 32));
        }
        asm volatile("s_waitcnt lgkmcnt(0)" ::: "memory");
        __builtin_amdgcn_sched_barrier(0);
        __builtin_amdgcn_s_setprio(1);
#pragma unroll
        for (int i = 0; i < 2; ++i)
#pragma unroll
            for (int j = 0; j < 4; ++j) {
                acc[2 + i][j] = __builtin_amdgcn_mfma_f32_16x16x32_bf16(av1[i][0], bv[j][0], acc[2 + i][j], 0, 0, 0);
                acc[2 + i][j] = __builtin_amdgcn_mfma_f32_16x16x32_bf16(av1[i][1], bv[j][1], acc[2 + i][j], 0, 0, 0);
            }
        __builtin_amdgcn_s_setprio(0);
        __builtin_amdgcn_s_barrier();           // buf rb reads done; next STAGE may overwrite

        rb = (rb + 1 == 3) ? 0 : rb + 1;
    }

    float bias[4];
#pragma unroll
    for (int j = 0; j < 4; ++j)
        bias[j] = b2[e * DM + n0 + wc * 64 + j * 16 + lrow];
#pragma unroll
    for (int i = 0; i < 4; ++i) {
        int gm = m0 + wr * 64 + i * 16 + qg * 4;
#pragma unroll
        for (int j = 0; j < 4; ++j) {
            int gn = n0 + wc * 64 + j * 16 + lrow;
#pragma unroll
            for (int r = 0; r < 4; ++r) {
                int row = gm + r;
                if (row < count)
                    h2[(size_t)(base + row) * DM + gn] = f2bf(acc[i][j][r] + bias[j]);
            }
        }
    }
}

// ---------------- finalize: 16 tokens/block, one WAVE per 4 tokens ----------------
__global__ __launch_bounds__(256) void finalize_kernel(
    const float* __restrict__ X, const int* __restrict__ type_seq,
    const int* __restrict__ pos_of, const int* __restrict__ cnt,
    const ushort* __restrict__ h2,
    const float* __restrict__ ln_g, const float* __restrict__ ln_b,
    const float* __restrict__ out_g, const float* __restrict__ out_b,
    float* __restrict__ out) {
    const int tid = threadIdx.x;
    const int wave = tid >> 6, lane = tid & 63;
    const int col0 = lane * 4;
    const int c0 = cnt[0], c1 = cnt[1], c2 = cnt[2];

#pragma unroll 1
    for (int ti = 0; ti < 4; ++ti) {
        const int t = blockIdx.x * 16 + wave * 4 + ti;
        const int k = type_seq[t];

        const float* Xr = X + (size_t)t * DM;
        float4 xv[3];
#pragma unroll
        for (int j = 0; j < 3; ++j) xv[j] = *(const float4*)(Xr + col0 + j * 256);

        float rv[12];
        if (k > 0) {
            const int e = k - 1;
            const int base = (e > 0) * c0 + (e > 1) * c1 + (e > 2) * c2;
            const size_t row = (size_t)(base + pos_of[t]);
            const ushort* hr = h2 + row * DM;
            float v[12];
            float s1 = 0.f, s2 = 0.f;
#pragma unroll
            for (int j = 0; j < 3; ++j) {
                ushort4 hv = *(const ushort4*)(hr + col0 + j * 256);
                float f0 = bf2f(hv.x) + xv[j].x;
                float f1 = bf2f(hv.y) + xv[j].y;
                float f2 = bf2f(hv.z) + xv[j].z;
                float f3 = bf2f(hv.w) + xv[j].w;
                v[j * 4 + 0] = f0; v[j * 4 + 1] = f1;
                v[j * 4 + 2] = f2; v[j * 4 + 3] = f3;
                s1 += (f0 + f1) + (f2 + f3);
                s2 += (f0 * f0 + f1 * f1) + (f2 * f2 + f3 * f3);
            }
#pragma unroll
            for (int off = 32; off > 0; off >>= 1) {
                s1 += __shfl_xor(s1, off, 64);
                s2 += __shfl_xor(s2, off, 64);
            }
            float m = s1 * (1.f / DM);
            float inv = rsqrtf(s2 * (1.f / DM) - m * m + 1e-12f);
#pragma unroll
            for (int j = 0; j < 3; ++j) {
                float4 g = *(const float4*)(ln_g + e * DM + col0 + j * 256);
                float4 b = *(const float4*)(ln_b + e * DM + col0 + j * 256);
                rv[j * 4 + 0] = (v[j * 4 + 0] - m) * inv * g.x + b.x;
                rv[j * 4 + 1] = (v[j * 4 + 1] - m) * inv * g.y + b.y;
                rv[j * 4 + 2] = (v[j * 4 + 2] - m) * inv * g.z + b.z;
                rv[j * 4 + 3] = (v[j * 4 + 3] - m) * inv * g.w + b.w;
            }
        } else {
#pragma unroll
            for (int j = 0; j < 12; ++j) rv[j] = 0.f;
        }

        float w[12];
        float s1 = 0.f, s2 = 0.f;
#pragma unroll
        for (int j = 0; j < 3; ++j) {
            float f0 = rv[j * 4 + 0] + xv[j].x;
            float f1 = rv[j * 4 + 1] + xv[j].y;
            float f2 = rv[j * 4 + 2] + xv[j].z;
            float f3 = rv[j * 4 + 3] + xv[j].w;
            w[j * 4 + 0] = f0; w[j * 4 + 1] = f1;
            w[j * 4 + 2] = f2; w[j * 4 + 3] = f3;
            s1 += (f0 + f1) + (f2 + f3);
            s2 += (f0 * f0 + f1 * f1) + (f2 * f2 + f3 * f3);
        }
#pragma unroll
        for (int off = 32; off > 0; off >>= 1) {
            s1 += __shfl_xor(s1, off, 64);
            s2 += __shfl_xor(s2, off, 64);
        }
        float m = s1 * (1.f / DM);
        float inv = rsqrtf(s2 * (1.f / DM) - m * m + 1e-12f);
#pragma unroll
        for (int j = 0; j < 3; ++j) {
            float4 g = *(const float4*)(out_g + col0 + j * 256);
            float4 b = *(const float4*)(out_b + col0 + j * 256);
            float4 o;
            o.x = (w[j * 4 + 0] - m) * inv * g.x + b.x;
            o.y = (w[j * 4 + 1] - m) * inv * g.y + b.y;
            o.z = (w[j * 4 + 2] - m) * inv * g.z + b.z;
            o.w = (w[j * 4 + 3] - m) * inv * g.w + b.w;
            *(float4*)(out + (size_t)t * DM + col0 + j * 256) = o;
        }
    }
}

// ---------------- launcher ----------------
extern "C" void kernel_launch(void* const* d_in, const int* in_sizes, int n_in,
                              void* d_out, int out_size, void* d_ws, size_t ws_size,
                              hipStream_t stream) {
    if (ws_size < (size_t)WS_END) return;

    const float* X     = (const float*)d_in[0];
    const int*   type  = (const int*)d_in[1];
    const float* W1    = (const float*)d_in[2];
    const float* b1    = (const float*)d_in[3];
    const float* W2    = (const float*)d_in[4];
    const float* b2    = (const float*)d_in[5];
    const float* ln_g  = (const float*)d_in[6];
    const float* ln_b  = (const float*)d_in[7];
    const float* out_g = (const float*)d_in[8];
    const float* out_b = (const float*)d_in[9];
    float* out = (float*)d_out;

    char* ws = (char*)d_ws;
    int* cnt    = (int*)(ws + WS_CNT);
    int* pos_of = (int*)(ws + WS_POS);
    int* list   = (int*)(ws + WS_LIST);
    ushort* Xb  = (ushort*)(ws + WS_XB);
    ushort* W1t = (ushort*)(ws + WS_W1T);
    ushort* W2t = (ushort*)(ws + WS_W2T);
    ushort* h1  = (ushort*)(ws + WS_H1);
    ushort* h2  = (ushort*)(ws + WS_H2);

    hipMemsetAsync(cnt, 0, NEXP * sizeof(int), stream);   // routing counters
    prep_kernel<<<PREP_BLKS, 256, 0, stream>>>(type, X, W1,
                                               cnt, pos_of, list, Xb, W1t);
    // gemm1 grid: up to 24*mb active tiles (mb<=131 -> T<=3144) + 288 W2-tail
    gemm1_kernel<<<dim3(24, 144), 512, 0, stream>>>(Xb, W1t, b1, cnt, list, h1, W2, W2t);
    // gemm2 grid: 6 n-blocks x up to 68 256-row panels
    gemm2_kernel<<<dim3(6, 68), 512, 0, stream>>>(h1, W2t, b2, cnt, h2);
    finalize_kernel<<<NTOK / 16, 256, 0, stream>>>(X, type, pos_of, cnt, h2, ln_g, ln_b, out_g, out_b, out);
}

// Round 14
// 373.767 us; speedup vs baseline: 1.1297x; 1.1297x over previous
//
#include <hip/hip_runtime.h>
#include <hip/hip_bf16.h>
#include <math.h>

#define NTOK   16384
#define DM     768
#define DF     3072
#define NEXP   4

// prep kernel fat-grid sections (routing + X cvt + W1 transpose;
// W2 transpose runs as tail blocks of gemm1, overlapped with compute)
#define RBLKS  64                      // routing: 256 tokens per block
#define XBLKS  768                     // X cvt: 8 units of 2048 elems each
#define WBLKS  288                     // W1 transpose: 8 tiles of 64x64 each
#define PREP_BLKS (RBLKS + XBLKS + WBLKS)   // 1120
#define W2BLKS 288                     // W2 transpose tail blocks inside gemm1

typedef short bf16x8 __attribute__((ext_vector_type(8)));
typedef float f32x4  __attribute__((ext_vector_type(4)));

// ---------------- workspace layout (bytes) ----------------
#define WS_CNT    0u
#define WS_BASES  256u                        // (unused slot, kept for layout stability)
#define WS_POS    512u                        // NTOK ints            = 65536
#define WS_LIST   (512u + 65536u)             // NEXP*NTOK ints       = 262144
#define WS_XB     (WS_LIST + 262144u)         // NTOK*DM bf16         = 25165824
#define WS_W1T    (WS_XB + 25165824u)         // 4*DF*DM bf16         = 18874368
#define WS_W2T    (WS_W1T + 18874368u)        // 4*DM*DF bf16         = 18874368
#define WS_H1     (WS_W2T + 18874368u)        // NTOK*DF bf16         = 100663296
#define WS_H2     (WS_H1 + 100663296u)        // NTOK*DM bf16         = 25165824
#define WS_END    (WS_H2 + 25165824u)

// ---------------- bf16 helpers (manual, RNE) ----------------
__device__ __forceinline__ ushort f2bf(float f) {
    unsigned int v; __builtin_memcpy(&v, &f, 4);
    v = v + 0x7fffu + ((v >> 16) & 1u);
    return (ushort)(v >> 16);
}
__device__ __forceinline__ float bf2f(ushort u) {
    unsigned int v = ((unsigned int)u) << 16;
    float f; __builtin_memcpy(&f, &v, 4); return f;
}

// fast gelu: x * sigmoid(1.5957691(x + 0.044715 x^3)); exp2-based, ~1e-3 abs err
__device__ __forceinline__ float fast_gelu(float v) {
    float y = v + 0.044715f * v * v * v;
    float e = __builtin_amdgcn_exp2f(-2.3022082f * y);
    return v * __builtin_amdgcn_rcpf(1.0f + e);
}

// async global->LDS, 16B per lane. LDS dest must be uniform_base + lane*16.
typedef __attribute__((address_space(1))) const void gvoid_t;
typedef __attribute__((address_space(3))) void lvoid_t;
__device__ __forceinline__ void cp16(const void* g, void* l) {
    __builtin_amdgcn_global_load_lds((gvoid_t*)g, (lvoid_t*)l, 16, 0, 0);
}

// bijective chunked XCD remap over T active blocks (m204 formula)
__device__ __forceinline__ int xcd_remap(int id, int T) {
    const int q = T >> 3, r = T & 7;
    const int x = id & 7, j = id >> 3;
    return (x < r ? x * (q + 1) : r * (q + 1) + (x - r) * q) + j;
}

// ---------------- prep: parallel routing + X cvt + W1 transpose ----------------
__global__ __launch_bounds__(256) void prep_kernel(
    const int* __restrict__ type_seq, const float* __restrict__ X,
    const float* __restrict__ W1,
    int* __restrict__ cnt,
    int* __restrict__ pos_of, int* __restrict__ list,
    ushort* __restrict__ Xb, ushort* __restrict__ W1t) {
    __shared__ ushort tbuf[2][64 * 72];
    __shared__ int lcnt[NEXP];
    __shared__ int lbase[NEXP];
    const int tid = threadIdx.x;
    const int bid = blockIdx.x;

    if (bid < RBLKS) {
        // ---- parallel routing: this block owns tokens [bid*256, bid*256+256) ----
        if (tid < NEXP) lcnt[tid] = 0;
        __syncthreads();
        const int lane = tid & 63;
        const int t = bid * 256 + tid;
        const int k = type_seq[t];
        int my_e = -1, my_p = 0;
#pragma unroll
        for (int e = 0; e < NEXP; ++e) {
            unsigned long long m = __ballot(k == e + 1);
            int total = __popcll(m);
            int b = 0;
            if (lane == 0 && total) b = atomicAdd(&lcnt[e], total);
            b = __shfl(b, 0, 64);
            if (k == e + 1) {
                my_e = e;
                my_p = b + __popcll(m & ((1ull << lane) - 1ull));
            }
        }
        __syncthreads();
        if (tid < NEXP && lcnt[tid] > 0)
            lbase[tid] = atomicAdd(&cnt[tid], lcnt[tid]);   // global, device-scope
        __syncthreads();
        if (my_e >= 0) {
            int gp = lbase[my_e] + my_p;
            list[my_e * NTOK + gp] = t;
            pos_of[t] = gp;
        }
        return;
    }

    int id = bid - RBLKS;
    if (id < XBLKS) {
        // ---- X fp32 -> bf16, 8 batched units per block ----
        size_t ibase = ((size_t)id * 8 * 256 + tid) * 8;
        float4 va[8], vb[8];
#pragma unroll
        for (int k = 0; k < 8; ++k) {
            va[k] = *(const float4*)(X + ibase + (size_t)k * 2048);
            vb[k] = *(const float4*)(X + ibase + (size_t)k * 2048 + 4);
        }
#pragma unroll
        for (int k = 0; k < 8; ++k) {
            ushort tmp[8];
            tmp[0] = f2bf(va[k].x); tmp[1] = f2bf(va[k].y);
            tmp[2] = f2bf(va[k].z); tmp[3] = f2bf(va[k].w);
            tmp[4] = f2bf(vb[k].x); tmp[5] = f2bf(vb[k].y);
            tmp[6] = f2bf(vb[k].z); tmp[7] = f2bf(vb[k].w);
            *(uint4*)(Xb + ibase + (size_t)k * 2048) = *(uint4*)tmp;
        }
        return;
    }
    id -= XBLKS;
    {
        // ---- W1 [z][768][3072] -> W1t [z][3072][768], 8 pipelined tiles ----
        const int lr = tid >> 3;            // 0..31
        const int lc = (tid & 7) * 8;       // 0,8,..,56
        float4 v[2][2];
        const int base_tt = id * 8;
        auto LOADT = [&](int tt) {
            int z = tt / 576, rr = tt % 576, bx = rr % 48, by = rr / 48;
            const float* s0 = W1 + (size_t)z * DM * DF + (size_t)(by * 64 + lr) * DF + bx * 64 + lc;
            v[0][0] = *(const float4*)s0;       v[0][1] = *(const float4*)(s0 + 4);
            const float* s1 = s0 + (size_t)32 * DF;
            v[1][0] = *(const float4*)s1;       v[1][1] = *(const float4*)(s1 + 4);
        };
        LOADT(base_tt);
#pragma unroll 1
        for (int k = 0; k < 8; ++k) {
            ushort* tb = &tbuf[k & 1][0];
#pragma unroll
            for (int q = 0; q < 2; ++q) {
                int r = lr + q * 32;
                ushort tmp[8];
                tmp[0] = f2bf(v[q][0].x); tmp[1] = f2bf(v[q][0].y);
                tmp[2] = f2bf(v[q][0].z); tmp[3] = f2bf(v[q][0].w);
                tmp[4] = f2bf(v[q][1].x); tmp[5] = f2bf(v[q][1].y);
                tmp[6] = f2bf(v[q][1].z); tmp[7] = f2bf(v[q][1].w);
                int sw = (((lc >> 3) ^ ((r >> 3) & 7)) << 3);
                *(uint4*)&tb[r * 72 + sw] = *(uint4*)tmp;
            }
            if (k < 7) LOADT(base_tt + k + 1);
            __syncthreads();
            int tt = base_tt + k;
            int z = tt / 576, rr = tt % 576, bx = rr % 48, by = rr / 48;
#pragma unroll
            for (int q = 0; q < 2; ++q) {
                int r = lr + q * 32;
                ushort tmp[8];
#pragma unroll
                for (int j = 0; j < 8; ++j)
                    tmp[j] = tb[(lc + j) * 72 +
                                ((((r >> 3) & 7) ^ (((lc + j) >> 3) & 7)) << 3) + (r & 7)];
                *(uint4*)(W1t + (size_t)z * DM * DF + (size_t)(bx * 64 + r) * DM + by * 64 + lc) = *(uint4*)tmp;
            }
        }
    }
}

// =====================================================================
// gemm1 (verified R9/R12 best): tile 128x128, 24 n-blocks, 512 thr = 8
// waves of 64x32 output. TRIPLE-buffered LDS (48 KiB, 3 blk/CU), depth-2
// prefetch, counted s_waitcnt vmcnt(2) + raw s_barrier; vmcnt(0) only at
// last iter. sched_barrier(0) pins ordering (rule #18). k-quad XOR
// swizzle (both-sides, conflict-free). XCD remap. Tail blocks (id >= T):
// W2 transpose, overlapped with gemm1 compute. Inline panel scan.
// Design-space note: {64x32,64x64,128x64}/wave x depth{1,2,3} + two
// deep-pipeline ports (R2/R8/R13) all measured; this is the optimum.
// =====================================================================
__global__ __launch_bounds__(512, 4) void gemm1_kernel(
    const ushort* __restrict__ Xb, const ushort* __restrict__ W1t,
    const float* __restrict__ b1, const int* __restrict__ cnt,
    const int* __restrict__ list, ushort* __restrict__ h1,
    const float* __restrict__ W2, ushort* __restrict__ W2t) {
    __shared__ __align__(16) short As[3][4096];
    __shared__ __align__(16) short Bs[3][4096];
    const int tid = threadIdx.x;

    const int c0 = cnt[0], c1 = cnt[1], c2 = cnt[2], c3 = cnt[3];
    const int p0 = (c0 + 127) >> 7, p1 = (c1 + 127) >> 7, p2 = (c2 + 127) >> 7;
    const int mb = p0 + p1 + p2 + ((c3 + 127) >> 7);
    const int T = mb * 24;
    int id = blockIdx.y * 24 + blockIdx.x;

    if (id >= T) {
        // ---------- W2 transpose tail blocks ----------
        int wid = id - T;
        if (wid >= W2BLKS) return;
        ushort* tb = (ushort*)&As[0][0];        // 9216 B scratch (spans As[0..1])
        const int lr = tid >> 3;                // 0..63
        const int lc = (tid & 7) * 8;           // 0..56
#pragma unroll 1
        for (int k = 0; k < 8; ++k) {
            int tt = wid * 8 + k;
            int zz = tt / 576, rr = tt % 576, bx = rr % 12, by = rr / 12;
            size_t mbase = (size_t)zz * DM * DF;
            const float* s = W2 + mbase + (size_t)(by * 64 + lr) * DM + bx * 64 + lc;
            float4 v0 = *(const float4*)s;
            float4 v1 = *(const float4*)(s + 4);
            ushort tmp[8];
            tmp[0] = f2bf(v0.x); tmp[1] = f2bf(v0.y); tmp[2] = f2bf(v0.z); tmp[3] = f2bf(v0.w);
            tmp[4] = f2bf(v1.x); tmp[5] = f2bf(v1.y); tmp[6] = f2bf(v1.z); tmp[7] = f2bf(v1.w);
            int sw = (((lc >> 3) ^ ((lr >> 3) & 7)) << 3);
            __syncthreads();                    // protect prior iter's reads
            *(uint4*)&tb[lr * 72 + sw] = *(uint4*)tmp;
            __syncthreads();
            ushort o[8];
#pragma unroll
            for (int j = 0; j < 8; ++j)
                o[j] = tb[(lc + j) * 72 +
                          ((((lr >> 3) & 7) ^ (((lc + j) >> 3) & 7)) << 3) + (lr & 7)];
            *(uint4*)(W2t + mbase + (size_t)(bx * 64 + lr) * DF + by * 64 + lc) = *(uint4*)o;
        }
        return;
    }

    id = xcd_remap(id, T);
    const int y = id / 24;
    const int n0 = (id % 24) * 128;
    const int q1 = p0, q2 = p0 + p1, q3 = p0 + p1 + p2;
    const int e = (y >= q1) + (y >= q2) + (y >= q3);
    const int mstart = (e > 0) * p0 + (e > 1) * p1 + (e > 2) * p2;
    const int m0 = (y - mstart) << 7;
    const int count = (e == 0) ? c0 : ((e == 1) ? c1 : ((e == 2) ? c2 : c3));
    const int base = (e > 0) * c0 + (e > 1) * c1 + (e > 2) * c2;
    const int NK = DM / 32;   // 24

    const int wave = tid >> 6, lane = tid & 63;
    const int wm = (wave & 1) * 64, wn = (wave >> 1) * 32;
    const int lrow = lane & 15;
    const int qg = lane >> 4;

    int r0 = min(m0 + (tid >> 2), count - 1);
    int t0 = list[e * NTOK + r0];
    const int qsrc = ((tid & 3) ^ ((tid >> 3) & 3)) * 8;   // source k-quad pre-swizzle
    const ushort* a0 = Xb + (size_t)t0 * DM + qsrc;
    const ushort* Wb = W1t + (size_t)e * DF * DM;
    const ushort* bp0 = Wb + (size_t)(n0 + (tid >> 2)) * DM + qsrc;

    int aOff[4], bOff[2];
#pragma unroll
    for (int i = 0; i < 4; ++i) {
        int ra = wm + i * 16 + lrow;
        aOff[i] = ra * 32 + (qg ^ ((ra >> 1) & 3)) * 8;
    }
#pragma unroll
    for (int j = 0; j < 2; ++j) {
        int rb = wn + j * 16 + lrow;
        bOff[j] = rb * 32 + (qg ^ ((rb >> 1) & 3)) * 8;
    }

    f32x4 z = {0.f, 0.f, 0.f, 0.f};
    f32x4 acc[4][2];
#pragma unroll
    for (int i = 0; i < 4; ++i)
#pragma unroll
        for (int j = 0; j < 2; ++j) acc[i][j] = z;

    auto STAGE = [&](int wb) {
        cp16(a0, &As[0][0] + wb * 4096 + tid * 8);
        cp16(bp0, &Bs[0][0] + wb * 4096 + tid * 8);
        a0 += 32; bp0 += 32;
    };

    STAGE(0); STAGE(1);                         // depth-2 prologue, 4 cp16 in flight
    int rb = 0;
    for (int ks = 0; ks < NK; ++ks) {
        __builtin_amdgcn_sched_barrier(0);
        if (ks + 1 < NK) { asm volatile("s_waitcnt vmcnt(2)" ::: "memory"); }
        else             { asm volatile("s_waitcnt vmcnt(0)" ::: "memory"); }
        __builtin_amdgcn_s_barrier();
        __builtin_amdgcn_sched_barrier(0);
        if (ks + 2 < NK) {
            int wb = rb - 1; if (wb < 0) wb += 3;   // (ks+2)%3
            STAGE(wb);
        }
        const short* Ab = &As[0][0] + rb * 4096;
        const short* Bb = &Bs[0][0] + rb * 4096;
        bf16x8 av[4], bv[2];
#pragma unroll
        for (int i = 0; i < 4; ++i) av[i] = *(const bf16x8*)(Ab + aOff[i]);
#pragma unroll
        for (int j = 0; j < 2; ++j) bv[j] = *(const bf16x8*)(Bb + bOff[j]);
#pragma unroll
        for (int i = 0; i < 4; ++i)
#pragma unroll
            for (int j = 0; j < 2; ++j)
                acc[i][j] = __builtin_amdgcn_mfma_f32_16x16x32_bf16(av[i], bv[j], acc[i][j], 0, 0, 0);
        rb = (rb + 1 == 3) ? 0 : rb + 1;
    }

    float bias[2];
#pragma unroll
    for (int nt = 0; nt < 2; ++nt)
        bias[nt] = b1[e * DF + n0 + wn + nt * 16 + lrow];
#pragma unroll
    for (int mt = 0; mt < 4; ++mt) {
        int gm = m0 + wm + mt * 16 + (lane >> 4) * 4;
#pragma unroll
        for (int nt = 0; nt < 2; ++nt) {
            int gn = n0 + wn + nt * 16 + lrow;
#pragma unroll
            for (int r = 0; r < 4; ++r) {
                int i = gm + r;
                if (i < count) {
                    float v = acc[mt][nt][r] + bias[nt];
                    h1[(size_t)(base + i) * DF + gn] = f2bf(fast_gelu(v));
                }
            }
        }
    }
}

// =====================================================================
// gemm2 (verified config): tile 128x128, 4 waves (2Mx2N) of 64x64,
// BK=32, triple-buffer depth-2 counted vmcnt(4). Inline panel scan.
// 618 blocks fit 3/CU in a single round.
// =====================================================================
__global__ __launch_bounds__(256, 3) void gemm2_kernel(
    const ushort* __restrict__ h1, const ushort* __restrict__ W2t,
    const float* __restrict__ b2, const int* __restrict__ cnt,
    ushort* __restrict__ h2) {
    const int c0 = cnt[0], c1 = cnt[1], c2 = cnt[2], c3 = cnt[3];
    const int p0 = (c0 + 127) >> 7, p1 = (c1 + 127) >> 7, p2 = (c2 + 127) >> 7;
    const int mb = p0 + p1 + p2 + ((c3 + 127) >> 7);
    const int T = mb * 6;
    int id = blockIdx.y * 6 + blockIdx.x;
    if (id >= T) return;
    id = xcd_remap(id, T);
    const int y = id / 6;
    const int n0 = (id % 6) * 128;
    const int q1 = p0, q2 = p0 + p1, q3 = p0 + p1 + p2;
    const int e = (y >= q1) + (y >= q2) + (y >= q3);
    const int mstart = (e > 0) * p0 + (e > 1) * p1 + (e > 2) * p2;
    const int m0 = (y - mstart) << 7;
    const int count = (e == 0) ? c0 : ((e == 1) ? c1 : ((e == 2) ? c2 : c3));
    const int base = (e > 0) * c0 + (e > 1) * c1 + (e > 2) * c2;
    const int NK = DF / 32;   // 96

    __shared__ __align__(16) short As[3][4096];
    __shared__ __align__(16) short Bs[3][4096];

    const int tid = threadIdx.x;
    const int wave = tid >> 6, lane = tid & 63;
    const int wm = (wave & 1) * 64, wn = (wave >> 1) * 64;
    const int lrow = lane & 15;
    const int qg = lane >> 4;

    const int srow = tid >> 2;                              // 0..63
    const int qsrc = ((tid & 3) ^ ((tid >> 3) & 3)) * 8;
    int r0 = min(m0 + srow, count - 1);
    int r1 = min(m0 + 64 + srow, count - 1);
    const ushort* a0 = h1 + (size_t)(base + r0) * DF + qsrc;
    const ushort* a1 = h1 + (size_t)(base + r1) * DF + qsrc;
    const ushort* Wb = W2t + (size_t)e * DM * DF;
    const ushort* bp0 = Wb + (size_t)(n0 + srow) * DF + qsrc;
    const ushort* bp1 = bp0 + (size_t)64 * DF;

    int aOff[4], bOff[4];
#pragma unroll
    for (int i = 0; i < 4; ++i) {
        int ra = wm + i * 16 + lrow;
        aOff[i] = ra * 32 + (qg ^ ((ra >> 1) & 3)) * 8;
        int rbo = wn + i * 16 + lrow;
        bOff[i] = rbo * 32 + (qg ^ ((rbo >> 1) & 3)) * 8;
    }

    f32x4 z = {0.f, 0.f, 0.f, 0.f};
    f32x4 acc[4][4];
#pragma unroll
    for (int i = 0; i < 4; ++i)
#pragma unroll
        for (int j = 0; j < 4; ++j) acc[i][j] = z;

    auto STAGE = [&](int wb) {
        cp16(a0, &As[wb][0] + tid * 8);
        cp16(a1, &As[wb][2048] + tid * 8);
        cp16(bp0, &Bs[wb][0] + tid * 8);
        cp16(bp1, &Bs[wb][2048] + tid * 8);
        a0 += 32; a1 += 32; bp0 += 32; bp1 += 32;
    };

    STAGE(0); STAGE(1);                         // depth-2 prologue, 8 cp16 in flight
    int rb = 0;
    for (int ks = 0; ks < NK; ++ks) {
        __builtin_amdgcn_sched_barrier(0);
        if (ks + 1 < NK) { asm volatile("s_waitcnt vmcnt(4)" ::: "memory"); }
        else             { asm volatile("s_waitcnt vmcnt(0)" ::: "memory"); }
        __builtin_amdgcn_s_barrier();
        __builtin_amdgcn_sched_barrier(0);
        if (ks + 2 < NK) {
            int wb = rb - 1; if (wb < 0) wb += 3;
            STAGE(wb);
        }
        const short* Ab = &As[rb][0];
        const short* Bb = &Bs[rb][0];
        bf16x8 av[4], bv[4];
#pragma unroll
        for (int i = 0; i < 4; ++i) av[i] = *(const bf16x8*)(Ab + aOff[i]);
#pragma unroll
        for (int j = 0; j < 4; ++j) bv[j] = *(const bf16x8*)(Bb + bOff[j]);
#pragma unroll
        for (int i = 0; i < 4; ++i)
#pragma unroll
            for (int j = 0; j < 4; ++j)
                acc[i][j] = __builtin_amdgcn_mfma_f32_16x16x32_bf16(av[i], bv[j], acc[i][j], 0, 0, 0);
        rb = (rb + 1 == 3) ? 0 : rb + 1;
    }

    float bias[4];
#pragma unroll
    for (int j = 0; j < 4; ++j)
        bias[j] = b2[e * DM + n0 + wn + j * 16 + lrow];
#pragma unroll
    for (int i = 0; i < 4; ++i) {
        int gm = m0 + wm + i * 16 + qg * 4;
#pragma unroll
        for (int j = 0; j < 4; ++j) {
            int gn = n0 + wn + j * 16 + lrow;
#pragma unroll
            for (int r = 0; r < 4; ++r) {
                int row = gm + r;
                if (row < count)
                    h2[(size_t)(base + row) * DM + gn] = f2bf(acc[i][j][r] + bias[j]);
            }
        }
    }
}

// ---------------- finalize: 16 tokens/block, one WAVE per 4 tokens ----------------
__global__ __launch_bounds__(256) void finalize_kernel(
    const float* __restrict__ X, const int* __restrict__ type_seq,
    const int* __restrict__ pos_of, const int* __restrict__ cnt,
    const ushort* __restrict__ h2,
    const float* __restrict__ ln_g, const float* __restrict__ ln_b,
    const float* __restrict__ out_g, const float* __restrict__ out_b,
    float* __restrict__ out) {
    const int tid = threadIdx.x;
    const int wave = tid >> 6, lane = tid & 63;
    const int col0 = lane * 4;
    const int c0 = cnt[0], c1 = cnt[1], c2 = cnt[2];

#pragma unroll 1
    for (int ti = 0; ti < 4; ++ti) {
        const int t = blockIdx.x * 16 + wave * 4 + ti;
        const int k = type_seq[t];

        const float* Xr = X + (size_t)t * DM;
        float4 xv[3];
#pragma unroll
        for (int j = 0; j < 3; ++j) xv[j] = *(const float4*)(Xr + col0 + j * 256);

        float rv[12];
        if (k > 0) {
            const int e = k - 1;
            const int base = (e > 0) * c0 + (e > 1) * c1 + (e > 2) * c2;
            const size_t row = (size_t)(base + pos_of[t]);
            const ushort* hr = h2 + row * DM;
            float v[12];
            float s1 = 0.f, s2 = 0.f;
#pragma unroll
            for (int j = 0; j < 3; ++j) {
                ushort4 hv = *(const ushort4*)(hr + col0 + j * 256);
                float f0 = bf2f(hv.x) + xv[j].x;
                float f1 = bf2f(hv.y) + xv[j].y;
                float f2 = bf2f(hv.z) + xv[j].z;
                float f3 = bf2f(hv.w) + xv[j].w;
                v[j * 4 + 0] = f0; v[j * 4 + 1] = f1;
                v[j * 4 + 2] = f2; v[j * 4 + 3] = f3;
                s1 += (f0 + f1) + (f2 + f3);
                s2 += (f0 * f0 + f1 * f1) + (f2 * f2 + f3 * f3);
            }
#pragma unroll
            for (int off = 32; off > 0; off >>= 1) {
                s1 += __shfl_xor(s1, off, 64);
                s2 += __shfl_xor(s2, off, 64);
            }
            float m = s1 * (1.f / DM);
            float inv = rsqrtf(s2 * (1.f / DM) - m * m + 1e-12f);
#pragma unroll
            for (int j = 0; j < 3; ++j) {
                float4 g = *(const float4*)(ln_g + e * DM + col0 + j * 256);
                float4 b = *(const float4*)(ln_b + e * DM + col0 + j * 256);
                rv[j * 4 + 0] = (v[j * 4 + 0] - m) * inv * g.x + b.x;
                rv[j * 4 + 1] = (v[j * 4 + 1] - m) * inv * g.y + b.y;
                rv[j * 4 + 2] = (v[j * 4 + 2] - m) * inv * g.z + b.z;
                rv[j * 4 + 3] = (v[j * 4 + 3] - m) * inv * g.w + b.w;
            }
        } else {
#pragma unroll
            for (int j = 0; j < 12; ++j) rv[j] = 0.f;
        }

        float w[12];
        float s1 = 0.f, s2 = 0.f;
#pragma unroll
        for (int j = 0; j < 3; ++j) {
            float f0 = rv[j * 4 + 0] + xv[j].x;
            float f1 = rv[j * 4 + 1] + xv[j].y;
            float f2 = rv[j * 4 + 2] + xv[j].z;
            float f3 = rv[j * 4 + 3] + xv[j].w;
            w[j * 4 + 0] = f0; w[j * 4 + 1] = f1;
            w[j * 4 + 2] = f2; w[j * 4 + 3] = f3;
            s1 += (f0 + f1) + (f2 + f3);
            s2 += (f0 * f0 + f1 * f1) + (f2 * f2 + f3 * f3);
        }
#pragma unroll
        for (int off = 32; off > 0; off >>= 1) {
            s1 += __shfl_xor(s1, off, 64);
            s2 += __shfl_xor(s2, off, 64);
        }
        float m = s1 * (1.f / DM);
        float inv = rsqrtf(s2 * (1.f / DM) - m * m + 1e-12f);
#pragma unroll
        for (int j = 0; j < 3; ++j) {
            float4 g = *(const float4*)(out_g + col0 + j * 256);
            float4 b = *(const float4*)(out_b + col0 + j * 256);
            float4 o;
            o.x = (w[j * 4 + 0] - m) * inv * g.x + b.x;
            o.y = (w[j * 4 + 1] - m) * inv * g.y + b.y;
            o.z = (w[j * 4 + 2] - m) * inv * g.z + b.z;
            o.w = (w[j * 4 + 3] - m) * inv * g.w + b.w;
            *(float4*)(out + (size_t)t * DM + col0 + j * 256) = o;
        }
    }
}

// ---------------- launcher ----------------
extern "C" void kernel_launch(void* const* d_in, const int* in_sizes, int n_in,
                              void* d_out, int out_size, void* d_ws, size_t ws_size,
                              hipStream_t stream) {
    if (ws_size < (size_t)WS_END) return;

    const float* X     = (const float*)d_in[0];
    const int*   type  = (const int*)d_in[1];
    const float* W1    = (const float*)d_in[2];
    const float* b1    = (const float*)d_in[3];
    const float* W2    = (const float*)d_in[4];
    const float* b2    = (const float*)d_in[5];
    const float* ln_g  = (const float*)d_in[6];
    const float* ln_b  = (const float*)d_in[7];
    const float* out_g = (const float*)d_in[8];
    const float* out_b = (const float*)d_in[9];
    float* out = (float*)d_out;

    char* ws = (char*)d_ws;
    int* cnt    = (int*)(ws + WS_CNT);
    int* pos_of = (int*)(ws + WS_POS);
    int* list   = (int*)(ws + WS_LIST);
    ushort* Xb  = (ushort*)(ws + WS_XB);
    ushort* W1t = (ushort*)(ws + WS_W1T);
    ushort* W2t = (ushort*)(ws + WS_W2T);
    ushort* h1  = (ushort*)(ws + WS_H1);
    ushort* h2  = (ushort*)(ws + WS_H2);

    hipMemsetAsync(cnt, 0, NEXP * sizeof(int), stream);   // routing counters
    prep_kernel<<<PREP_BLKS, 256, 0, stream>>>(type, X, W1,
                                               cnt, pos_of, list, Xb, W1t);
    // gemm1 grid: up to 24*mb active tiles (mb<=131 -> T<=3144) + 288 W2-tail
    gemm1_kernel<<<dim3(24, 144), 512, 0, stream>>>(Xb, W1t, b1, cnt, list, h1, W2, W2t);
    gemm2_kernel<<<dim3(6, 132), 256, 0, stream>>>(h1, W2t, b2, cnt, h2);
    finalize_kernel<<<NTOK / 16, 256, 0, stream>>>(X, type, pos_of, cnt, h2, ln_g, ln_b, out_g, out_b, out);
}

// Round 15
// 368.512 us; speedup vs baseline: 1.1458x; 1.0143x over previous
//
#include <hip/hip_runtime.h>
#include <hip/hip_bf16.h>
#include <math.h>

#define NTOK   16384
#define DM     768
#define DF     3072
#define NEXP   4

// prep kernel fat-grid sections (routing + X cvt + W1 transpose;
// W2 transpose runs as tail blocks of gemm1, overlapped with compute)
#define RBLKS  64                      // routing: 256 tokens per block
#define XBLKS  768                     // X cvt: 8 units of 2048 elems each
#define WBLKS  1152                    // W1 transpose: 2 tiles of 64x64 each (rebalanced)
#define PREP_BLKS (RBLKS + XBLKS + WBLKS)   // 1984
#define W2BLKS 288                     // W2 transpose tail blocks inside gemm1

typedef short bf16x8 __attribute__((ext_vector_type(8)));
typedef float f32x4  __attribute__((ext_vector_type(4)));

// ---------------- workspace layout (bytes) ----------------
#define WS_CNT    0u
#define WS_BASES  256u                        // (unused slot, kept for layout stability)
#define WS_POS    512u                        // NTOK ints            = 65536
#define WS_LIST   (512u + 65536u)             // NEXP*NTOK ints       = 262144
#define WS_XB     (WS_LIST + 262144u)         // NTOK*DM bf16         = 25165824
#define WS_W1T    (WS_XB + 25165824u)         // 4*DF*DM bf16         = 18874368
#define WS_W2T    (WS_W1T + 18874368u)        // 4*DM*DF bf16         = 18874368
#define WS_H1     (WS_W2T + 18874368u)        // NTOK*DF bf16         = 100663296
#define WS_H2     (WS_H1 + 100663296u)        // NTOK*DM bf16         = 25165824
#define WS_END    (WS_H2 + 25165824u)

// ---------------- bf16 helpers (manual, RNE) ----------------
__device__ __forceinline__ ushort f2bf(float f) {
    unsigned int v; __builtin_memcpy(&v, &f, 4);
    v = v + 0x7fffu + ((v >> 16) & 1u);
    return (ushort)(v >> 16);
}
__device__ __forceinline__ float bf2f(ushort u) {
    unsigned int v = ((unsigned int)u) << 16;
    float f; __builtin_memcpy(&f, &v, 4); return f;
}

// fast gelu: x * sigmoid(1.5957691(x + 0.044715 x^3)); exp2-based, ~1e-3 abs err
__device__ __forceinline__ float fast_gelu(float v) {
    float y = v + 0.044715f * v * v * v;
    float e = __builtin_amdgcn_exp2f(-2.3022082f * y);
    return v * __builtin_amdgcn_rcpf(1.0f + e);
}

// async global->LDS, 16B per lane. LDS dest must be uniform_base + lane*16.
typedef __attribute__((address_space(1))) const void gvoid_t;
typedef __attribute__((address_space(3))) void lvoid_t;
__device__ __forceinline__ void cp16(const void* g, void* l) {
    __builtin_amdgcn_global_load_lds((gvoid_t*)g, (lvoid_t*)l, 16, 0, 0);
}

// bijective chunked XCD remap over T active blocks (m204 formula)
__device__ __forceinline__ int xcd_remap(int id, int T) {
    const int q = T >> 3, r = T & 7;
    const int x = id & 7, j = id >> 3;
    return (x < r ? x * (q + 1) : r * (q + 1) + (x - r) * q) + j;
}

// ---------------- prep: parallel routing + X cvt + W1 transpose ----------------
__global__ __launch_bounds__(256) void prep_kernel(
    const int* __restrict__ type_seq, const float* __restrict__ X,
    const float* __restrict__ W1,
    int* __restrict__ cnt,
    int* __restrict__ pos_of, int* __restrict__ list,
    ushort* __restrict__ Xb, ushort* __restrict__ W1t) {
    __shared__ ushort tbuf[2][64 * 72];
    __shared__ int lcnt[NEXP];
    __shared__ int lbase[NEXP];
    const int tid = threadIdx.x;
    const int bid = blockIdx.x;

    if (bid < RBLKS) {
        // ---- parallel routing: this block owns tokens [bid*256, bid*256+256) ----
        if (tid < NEXP) lcnt[tid] = 0;
        __syncthreads();
        const int lane = tid & 63;
        const int t = bid * 256 + tid;
        const int k = type_seq[t];
        int my_e = -1, my_p = 0;
#pragma unroll
        for (int e = 0; e < NEXP; ++e) {
            unsigned long long m = __ballot(k == e + 1);
            int total = __popcll(m);
            int b = 0;
            if (lane == 0 && total) b = atomicAdd(&lcnt[e], total);
            b = __shfl(b, 0, 64);
            if (k == e + 1) {
                my_e = e;
                my_p = b + __popcll(m & ((1ull << lane) - 1ull));
            }
        }
        __syncthreads();
        if (tid < NEXP && lcnt[tid] > 0)
            lbase[tid] = atomicAdd(&cnt[tid], lcnt[tid]);   // global, device-scope
        __syncthreads();
        if (my_e >= 0) {
            int gp = lbase[my_e] + my_p;
            list[my_e * NTOK + gp] = t;
            pos_of[t] = gp;
        }
        return;
    }

    int id = bid - RBLKS;
    if (id < XBLKS) {
        // ---- X fp32 -> bf16, 8 batched units per block ----
        size_t ibase = ((size_t)id * 8 * 256 + tid) * 8;
        float4 va[8], vb[8];
#pragma unroll
        for (int k = 0; k < 8; ++k) {
            va[k] = *(const float4*)(X + ibase + (size_t)k * 2048);
            vb[k] = *(const float4*)(X + ibase + (size_t)k * 2048 + 4);
        }
#pragma unroll
        for (int k = 0; k < 8; ++k) {
            ushort tmp[8];
            tmp[0] = f2bf(va[k].x); tmp[1] = f2bf(va[k].y);
            tmp[2] = f2bf(va[k].z); tmp[3] = f2bf(va[k].w);
            tmp[4] = f2bf(vb[k].x); tmp[5] = f2bf(vb[k].y);
            tmp[6] = f2bf(vb[k].z); tmp[7] = f2bf(vb[k].w);
            *(uint4*)(Xb + ibase + (size_t)k * 2048) = *(uint4*)tmp;
        }
        return;
    }
    id -= XBLKS;
    {
        // ---- W1 [z][768][3072] -> W1t [z][3072][768], 2 pipelined tiles ----
        // (rebalanced from 288x8 to 1152x2: 4x latency-hiding parallelism)
        const int lr = tid >> 3;            // 0..31
        const int lc = (tid & 7) * 8;       // 0,8,..,56
        float4 v[2][2];
        const int base_tt = id * 2;
        auto LOADT = [&](int tt) {
            int z = tt / 576, rr = tt % 576, bx = rr % 48, by = rr / 48;
            const float* s0 = W1 + (size_t)z * DM * DF + (size_t)(by * 64 + lr) * DF + bx * 64 + lc;
            v[0][0] = *(const float4*)s0;       v[0][1] = *(const float4*)(s0 + 4);
            const float* s1 = s0 + (size_t)32 * DF;
            v[1][0] = *(const float4*)s1;       v[1][1] = *(const float4*)(s1 + 4);
        };
        LOADT(base_tt);
#pragma unroll 1
        for (int k = 0; k < 2; ++k) {
            ushort* tb = &tbuf[k & 1][0];
#pragma unroll
            for (int q = 0; q < 2; ++q) {
                int r = lr + q * 32;
                ushort tmp[8];
                tmp[0] = f2bf(v[q][0].x); tmp[1] = f2bf(v[q][0].y);
                tmp[2] = f2bf(v[q][0].z); tmp[3] = f2bf(v[q][0].w);
                tmp[4] = f2bf(v[q][1].x); tmp[5] = f2bf(v[q][1].y);
                tmp[6] = f2bf(v[q][1].z); tmp[7] = f2bf(v[q][1].w);
                int sw = (((lc >> 3) ^ ((r >> 3) & 7)) << 3);
                *(uint4*)&tb[r * 72 + sw] = *(uint4*)tmp;
            }
            if (k < 1) LOADT(base_tt + k + 1);
            __syncthreads();
            int tt = base_tt + k;
            int z = tt / 576, rr = tt % 576, bx = rr % 48, by = rr / 48;
#pragma unroll
            for (int q = 0; q < 2; ++q) {
                int r = lr + q * 32;
                ushort tmp[8];
#pragma unroll
                for (int j = 0; j < 8; ++j)
                    tmp[j] = tb[(lc + j) * 72 +
                                ((((r >> 3) & 7) ^ (((lc + j) >> 3) & 7)) << 3) + (r & 7)];
                *(uint4*)(W1t + (size_t)z * DM * DF + (size_t)(bx * 64 + r) * DM + by * 64 + lc) = *(uint4*)tmp;
            }
        }
    }
}

// =====================================================================
// gemm1 (verified R9/R12 best): tile 128x128, 24 n-blocks, 512 thr = 8
// waves of 64x32 output. TRIPLE-buffered LDS (48 KiB, 3 blk/CU), depth-2
// prefetch, counted s_waitcnt vmcnt(2) + raw s_barrier; vmcnt(0) only at
// last iter. sched_barrier(0) pins ordering (rule #18). k-quad XOR
// swizzle (both-sides, conflict-free). XCD remap. Tail blocks (id >= T):
// W2 transpose, overlapped with gemm1 compute. Inline panel scan.
// =====================================================================
__global__ __launch_bounds__(512, 4) void gemm1_kernel(
    const ushort* __restrict__ Xb, const ushort* __restrict__ W1t,
    const float* __restrict__ b1, const int* __restrict__ cnt,
    const int* __restrict__ list, ushort* __restrict__ h1,
    const float* __restrict__ W2, ushort* __restrict__ W2t) {
    __shared__ __align__(16) short As[3][4096];
    __shared__ __align__(16) short Bs[3][4096];
    const int tid = threadIdx.x;

    const int c0 = cnt[0], c1 = cnt[1], c2 = cnt[2], c3 = cnt[3];
    const int p0 = (c0 + 127) >> 7, p1 = (c1 + 127) >> 7, p2 = (c2 + 127) >> 7;
    const int mb = p0 + p1 + p2 + ((c3 + 127) >> 7);
    const int T = mb * 24;
    int id = blockIdx.y * 24 + blockIdx.x;

    if (id >= T) {
        // ---------- W2 transpose tail blocks ----------
        int wid = id - T;
        if (wid >= W2BLKS) return;
        ushort* tb = (ushort*)&As[0][0];        // 9216 B scratch (spans As[0..1])
        const int lr = tid >> 3;                // 0..63
        const int lc = (tid & 7) * 8;           // 0..56
#pragma unroll 1
        for (int k = 0; k < 8; ++k) {
            int tt = wid * 8 + k;
            int zz = tt / 576, rr = tt % 576, bx = rr % 12, by = rr / 12;
            size_t mbase = (size_t)zz * DM * DF;
            const float* s = W2 + mbase + (size_t)(by * 64 + lr) * DM + bx * 64 + lc;
            float4 v0 = *(const float4*)s;
            float4 v1 = *(const float4*)(s + 4);
            ushort tmp[8];
            tmp[0] = f2bf(v0.x); tmp[1] = f2bf(v0.y); tmp[2] = f2bf(v0.z); tmp[3] = f2bf(v0.w);
            tmp[4] = f2bf(v1.x); tmp[5] = f2bf(v1.y); tmp[6] = f2bf(v1.z); tmp[7] = f2bf(v1.w);
            int sw = (((lc >> 3) ^ ((lr >> 3) & 7)) << 3);
            __syncthreads();                    // protect prior iter's reads
            *(uint4*)&tb[lr * 72 + sw] = *(uint4*)tmp;
            __syncthreads();
            ushort o[8];
#pragma unroll
            for (int j = 0; j < 8; ++j)
                o[j] = tb[(lc + j) * 72 +
                          ((((lr >> 3) & 7) ^ (((lc + j) >> 3) & 7)) << 3) + (lr & 7)];
            *(uint4*)(W2t + mbase + (size_t)(bx * 64 + lr) * DF + by * 64 + lc) = *(uint4*)o;
        }
        return;
    }

    id = xcd_remap(id, T);
    const int y = id / 24;
    const int n0 = (id % 24) * 128;
    const int q1 = p0, q2 = p0 + p1, q3 = p0 + p1 + p2;
    const int e = (y >= q1) + (y >= q2) + (y >= q3);
    const int mstart = (e > 0) * p0 + (e > 1) * p1 + (e > 2) * p2;
    const int m0 = (y - mstart) << 7;
    const int count = (e == 0) ? c0 : ((e == 1) ? c1 : ((e == 2) ? c2 : c3));
    const int base = (e > 0) * c0 + (e > 1) * c1 + (e > 2) * c2;
    const int NK = DM / 32;   // 24

    const int wave = tid >> 6, lane = tid & 63;
    const int wm = (wave & 1) * 64, wn = (wave >> 1) * 32;
    const int lrow = lane & 15;
    const int qg = lane >> 4;

    int r0 = min(m0 + (tid >> 2), count - 1);
    int t0 = list[e * NTOK + r0];
    const int qsrc = ((tid & 3) ^ ((tid >> 3) & 3)) * 8;   // source k-quad pre-swizzle
    const ushort* a0 = Xb + (size_t)t0 * DM + qsrc;
    const ushort* Wb = W1t + (size_t)e * DF * DM;
    const ushort* bp0 = Wb + (size_t)(n0 + (tid >> 2)) * DM + qsrc;

    int aOff[4], bOff[2];
#pragma unroll
    for (int i = 0; i < 4; ++i) {
        int ra = wm + i * 16 + lrow;
        aOff[i] = ra * 32 + (qg ^ ((ra >> 1) & 3)) * 8;
    }
#pragma unroll
    for (int j = 0; j < 2; ++j) {
        int rb = wn + j * 16 + lrow;
        bOff[j] = rb * 32 + (qg ^ ((rb >> 1) & 3)) * 8;
    }

    f32x4 z = {0.f, 0.f, 0.f, 0.f};
    f32x4 acc[4][2];
#pragma unroll
    for (int i = 0; i < 4; ++i)
#pragma unroll
        for (int j = 0; j < 2; ++j) acc[i][j] = z;

    auto STAGE = [&](int wb) {
        cp16(a0, &As[0][0] + wb * 4096 + tid * 8);
        cp16(bp0, &Bs[0][0] + wb * 4096 + tid * 8);
        a0 += 32; bp0 += 32;
    };

    STAGE(0); STAGE(1);                         // depth-2 prologue, 4 cp16 in flight
    int rb = 0;
    for (int ks = 0; ks < NK; ++ks) {
        __builtin_amdgcn_sched_barrier(0);
        if (ks + 1 < NK) { asm volatile("s_waitcnt vmcnt(2)" ::: "memory"); }
        else             { asm volatile("s_waitcnt vmcnt(0)" ::: "memory"); }
        __builtin_amdgcn_s_barrier();
        __builtin_amdgcn_sched_barrier(0);
        if (ks + 2 < NK) {
            int wb = rb - 1; if (wb < 0) wb += 3;   // (ks+2)%3
            STAGE(wb);
        }
        const short* Ab = &As[0][0] + rb * 4096;
        const short* Bb = &Bs[0][0] + rb * 4096;
        bf16x8 av[4], bv[2];
#pragma unroll
        for (int i = 0; i < 4; ++i) av[i] = *(const bf16x8*)(Ab + aOff[i]);
#pragma unroll
        for (int j = 0; j < 2; ++j) bv[j] = *(const bf16x8*)(Bb + bOff[j]);
#pragma unroll
        for (int i = 0; i < 4; ++i)
#pragma unroll
            for (int j = 0; j < 2; ++j)
                acc[i][j] = __builtin_amdgcn_mfma_f32_16x16x32_bf16(av[i], bv[j], acc[i][j], 0, 0, 0);
        rb = (rb + 1 == 3) ? 0 : rb + 1;
    }

    float bias[2];
#pragma unroll
    for (int nt = 0; nt < 2; ++nt)
        bias[nt] = b1[e * DF + n0 + wn + nt * 16 + lrow];
#pragma unroll
    for (int mt = 0; mt < 4; ++mt) {
        int gm = m0 + wm + mt * 16 + (lane >> 4) * 4;
#pragma unroll
        for (int nt = 0; nt < 2; ++nt) {
            int gn = n0 + wn + nt * 16 + lrow;
#pragma unroll
            for (int r = 0; r < 4; ++r) {
                int i = gm + r;
                if (i < count) {
                    float v = acc[mt][nt][r] + bias[nt];
                    h1[(size_t)(base + i) * DF + gn] = f2bf(fast_gelu(v));
                }
            }
        }
    }
}

// =====================================================================
// gemm2 (verified config): tile 128x128, 4 waves (2Mx2N) of 64x64,
// BK=32, triple-buffer depth-2 counted vmcnt(4). Inline panel scan.
// 618 blocks fit 3/CU in a single round.
// =====================================================================
__global__ __launch_bounds__(256, 3) void gemm2_kernel(
    const ushort* __restrict__ h1, const ushort* __restrict__ W2t,
    const float* __restrict__ b2, const int* __restrict__ cnt,
    ushort* __restrict__ h2) {
    const int c0 = cnt[0], c1 = cnt[1], c2 = cnt[2], c3 = cnt[3];
    const int p0 = (c0 + 127) >> 7, p1 = (c1 + 127) >> 7, p2 = (c2 + 127) >> 7;
    const int mb = p0 + p1 + p2 + ((c3 + 127) >> 7);
    const int T = mb * 6;
    int id = blockIdx.y * 6 + blockIdx.x;
    if (id >= T) return;
    id = xcd_remap(id, T);
    const int y = id / 6;
    const int n0 = (id % 6) * 128;
    const int q1 = p0, q2 = p0 + p1, q3 = p0 + p1 + p2;
    const int e = (y >= q1) + (y >= q2) + (y >= q3);
    const int mstart = (e > 0) * p0 + (e > 1) * p1 + (e > 2) * p2;
    const int m0 = (y - mstart) << 7;
    const int count = (e == 0) ? c0 : ((e == 1) ? c1 : ((e == 2) ? c2 : c3));
    const int base = (e > 0) * c0 + (e > 1) * c1 + (e > 2) * c2;
    const int NK = DF / 32;   // 96

    __shared__ __align__(16) short As[3][4096];
    __shared__ __align__(16) short Bs[3][4096];

    const int tid = threadIdx.x;
    const int wave = tid >> 6, lane = tid & 63;
    const int wm = (wave & 1) * 64, wn = (wave >> 1) * 64;
    const int lrow = lane & 15;
    const int qg = lane >> 4;

    const int srow = tid >> 2;                              // 0..63
    const int qsrc = ((tid & 3) ^ ((tid >> 3) & 3)) * 8;
    int r0 = min(m0 + srow, count - 1);
    int r1 = min(m0 + 64 + srow, count - 1);
    const ushort* a0 = h1 + (size_t)(base + r0) * DF + qsrc;
    const ushort* a1 = h1 + (size_t)(base + r1) * DF + qsrc;
    const ushort* Wb = W2t + (size_t)e * DM * DF;
    const ushort* bp0 = Wb + (size_t)(n0 + srow) * DF + qsrc;
    const ushort* bp1 = bp0 + (size_t)64 * DF;

    int aOff[4], bOff[4];
#pragma unroll
    for (int i = 0; i < 4; ++i) {
        int ra = wm + i * 16 + lrow;
        aOff[i] = ra * 32 + (qg ^ ((ra >> 1) & 3)) * 8;
        int rbo = wn + i * 16 + lrow;
        bOff[i] = rbo * 32 + (qg ^ ((rbo >> 1) & 3)) * 8;
    }

    f32x4 z = {0.f, 0.f, 0.f, 0.f};
    f32x4 acc[4][4];
#pragma unroll
    for (int i = 0; i < 4; ++i)
#pragma unroll
        for (int j = 0; j < 4; ++j) acc[i][j] = z;

    auto STAGE = [&](int wb) {
        cp16(a0, &As[wb][0] + tid * 8);
        cp16(a1, &As[wb][2048] + tid * 8);
        cp16(bp0, &Bs[wb][0] + tid * 8);
        cp16(bp1, &Bs[wb][2048] + tid * 8);
        a0 += 32; a1 += 32; bp0 += 32; bp1 += 32;
    };

    STAGE(0); STAGE(1);                         // depth-2 prologue, 8 cp16 in flight
    int rb = 0;
    for (int ks = 0; ks < NK; ++ks) {
        __builtin_amdgcn_sched_barrier(0);
        if (ks + 1 < NK) { asm volatile("s_waitcnt vmcnt(4)" ::: "memory"); }
        else             { asm volatile("s_waitcnt vmcnt(0)" ::: "memory"); }
        __builtin_amdgcn_s_barrier();
        __builtin_amdgcn_sched_barrier(0);
        if (ks + 2 < NK) {
            int wb = rb - 1; if (wb < 0) wb += 3;
            STAGE(wb);
        }
        const short* Ab = &As[rb][0];
        const short* Bb = &Bs[rb][0];
        bf16x8 av[4], bv[4];
#pragma unroll
        for (int i = 0; i < 4; ++i) av[i] = *(const bf16x8*)(Ab + aOff[i]);
#pragma unroll
        for (int j = 0; j < 4; ++j) bv[j] = *(const bf16x8*)(Bb + bOff[j]);
#pragma unroll
        for (int i = 0; i < 4; ++i)
#pragma unroll
            for (int j = 0; j < 4; ++j)
                acc[i][j] = __builtin_amdgcn_mfma_f32_16x16x32_bf16(av[i], bv[j], acc[i][j], 0, 0, 0);
        rb = (rb + 1 == 3) ? 0 : rb + 1;
    }

    float bias[4];
#pragma unroll
    for (int j = 0; j < 4; ++j)
        bias[j] = b2[e * DM + n0 + wn + j * 16 + lrow];
#pragma unroll
    for (int i = 0; i < 4; ++i) {
        int gm = m0 + wm + i * 16 + qg * 4;
#pragma unroll
        for (int j = 0; j < 4; ++j) {
            int gn = n0 + wn + j * 16 + lrow;
#pragma unroll
            for (int r = 0; r < 4; ++r) {
                int row = gm + r;
                if (row < count)
                    h2[(size_t)(base + row) * DM + gn] = f2bf(acc[i][j][r] + bias[j]);
            }
        }
    }
}

// ---------------- finalize: 16 tokens/block, one WAVE per 4 tokens ----------------
__global__ __launch_bounds__(256) void finalize_kernel(
    const float* __restrict__ X, const int* __restrict__ type_seq,
    const int* __restrict__ pos_of, const int* __restrict__ cnt,
    const ushort* __restrict__ h2,
    const float* __restrict__ ln_g, const float* __restrict__ ln_b,
    const float* __restrict__ out_g, const float* __restrict__ out_b,
    float* __restrict__ out) {
    const int tid = threadIdx.x;
    const int wave = tid >> 6, lane = tid & 63;
    const int col0 = lane * 4;
    const int c0 = cnt[0], c1 = cnt[1], c2 = cnt[2];

#pragma unroll 1
    for (int ti = 0; ti < 4; ++ti) {
        const int t = blockIdx.x * 16 + wave * 4 + ti;
        const int k = type_seq[t];

        const float* Xr = X + (size_t)t * DM;
        float4 xv[3];
#pragma unroll
        for (int j = 0; j < 3; ++j) xv[j] = *(const float4*)(Xr + col0 + j * 256);

        float rv[12];
        if (k > 0) {
            const int e = k - 1;
            const int base = (e > 0) * c0 + (e > 1) * c1 + (e > 2) * c2;
            const size_t row = (size_t)(base + pos_of[t]);
            const ushort* hr = h2 + row * DM;
            float v[12];
            float s1 = 0.f, s2 = 0.f;
#pragma unroll
            for (int j = 0; j < 3; ++j) {
                ushort4 hv = *(const ushort4*)(hr + col0 + j * 256);
                float f0 = bf2f(hv.x) + xv[j].x;
                float f1 = bf2f(hv.y) + xv[j].y;
                float f2 = bf2f(hv.z) + xv[j].z;
                float f3 = bf2f(hv.w) + xv[j].w;
                v[j * 4 + 0] = f0; v[j * 4 + 1] = f1;
                v[j * 4 + 2] = f2; v[j * 4 + 3] = f3;
                s1 += (f0 + f1) + (f2 + f3);
                s2 += (f0 * f0 + f1 * f1) + (f2 * f2 + f3 * f3);
            }
#pragma unroll
            for (int off = 32; off > 0; off >>= 1) {
                s1 += __shfl_xor(s1, off, 64);
                s2 += __shfl_xor(s2, off, 64);
            }
            float m = s1 * (1.f / DM);
            float inv = rsqrtf(s2 * (1.f / DM) - m * m + 1e-12f);
#pragma unroll
            for (int j = 0; j < 3; ++j) {
                float4 g = *(const float4*)(ln_g + e * DM + col0 + j * 256);
                float4 b = *(const float4*)(ln_b + e * DM + col0 + j * 256);
                rv[j * 4 + 0] = (v[j * 4 + 0] - m) * inv * g.x + b.x;
                rv[j * 4 + 1] = (v[j * 4 + 1] - m) * inv * g.y + b.y;
                rv[j * 4 + 2] = (v[j * 4 + 2] - m) * inv * g.z + b.z;
                rv[j * 4 + 3] = (v[j * 4 + 3] - m) * inv * g.w + b.w;
            }
        } else {
#pragma unroll
            for (int j = 0; j < 12; ++j) rv[j] = 0.f;
        }

        float w[12];
        float s1 = 0.f, s2 = 0.f;
#pragma unroll
        for (int j = 0; j < 3; ++j) {
            float f0 = rv[j * 4 + 0] + xv[j].x;
            float f1 = rv[j * 4 + 1] + xv[j].y;
            float f2 = rv[j * 4 + 2] + xv[j].z;
            float f3 = rv[j * 4 + 3] + xv[j].w;
            w[j * 4 + 0] = f0; w[j * 4 + 1] = f1;
            w[j * 4 + 2] = f2; w[j * 4 + 3] = f3;
            s1 += (f0 + f1) + (f2 + f3);
            s2 += (f0 * f0 + f1 * f1) + (f2 * f2 + f3 * f3);
        }
#pragma unroll
        for (int off = 32; off > 0; off >>= 1) {
            s1 += __shfl_xor(s1, off, 64);
            s2 += __shfl_xor(s2, off, 64);
        }
        float m = s1 * (1.f / DM);
        float inv = rsqrtf(s2 * (1.f / DM) - m * m + 1e-12f);
#pragma unroll
        for (int j = 0; j < 3; ++j) {
            float4 g = *(const float4*)(out_g + col0 + j * 256);
            float4 b = *(const float4*)(out_b + col0 + j * 256);
            float4 o;
            o.x = (w[j * 4 + 0] - m) * inv * g.x + b.x;
            o.y = (w[j * 4 + 1] - m) * inv * g.y + b.y;
            o.z = (w[j * 4 + 2] - m) * inv * g.z + b.z;
            o.w = (w[j * 4 + 3] - m) * inv * g.w + b.w;
            *(float4*)(out + (size_t)t * DM + col0 + j * 256) = o;
        }
    }
}

// ---------------- launcher ----------------
extern "C" void kernel_launch(void* const* d_in, const int* in_sizes, int n_in,
                              void* d_out, int out_size, void* d_ws, size_t ws_size,
                              hipStream_t stream) {
    if (ws_size < (size_t)WS_END) return;

    const float* X     = (const float*)d_in[0];
    const int*   type  = (const int*)d_in[1];
    const float* W1    = (const float*)d_in[2];
    const float* b1    = (const float*)d_in[3];
    const float* W2    = (const float*)d_in[4];
    const float* b2    = (const float*)d_in[5];
    const float* ln_g  = (const float*)d_in[6];
    const float* ln_b  = (const float*)d_in[7];
    const float* out_g = (const float*)d_in[8];
    const float* out_b = (const float*)d_in[9];
    float* out = (float*)d_out;

    char* ws = (char*)d_ws;
    int* cnt    = (int*)(ws + WS_CNT);
    int* pos_of = (int*)(ws + WS_POS);
    int* list   = (int*)(ws + WS_LIST);
    ushort* Xb  = (ushort*)(ws + WS_XB);
    ushort* W1t = (ushort*)(ws + WS_W1T);
    ushort* W2t = (ushort*)(ws + WS_W2T);
    ushort* h1  = (ushort*)(ws + WS_H1);
    ushort* h2  = (ushort*)(ws + WS_H2);

    hipMemsetAsync(cnt, 0, NEXP * sizeof(int), stream);   // routing counters
    prep_kernel<<<PREP_BLKS, 256, 0, stream>>>(type, X, W1,
                                               cnt, pos_of, list, Xb, W1t);
    // gemm1 grid: up to 24*mb active tiles (mb<=131 -> T<=3144) + 288 W2-tail
    gemm1_kernel<<<dim3(24, 144), 512, 0, stream>>>(Xb, W1t, b1, cnt, list, h1, W2, W2t);
    gemm2_kernel<<<dim3(6, 132), 256, 0, stream>>>(h1, W2t, b2, cnt, h2);
    finalize_kernel<<<NTOK / 16, 256, 0, stream>>>(X, type, pos_of, cnt, h2, ln_g, ln_b, out_g, out_b, out);
}

// Round 16
// 367.654 us; speedup vs baseline: 1.1485x; 1.0023x over previous
//
#include <hip/hip_runtime.h>
#include <hip/hip_bf16.h>
#include <math.h>

#define NTOK   16384
#define DM     768
#define DF     3072
#define NEXP   4

// prep kernel fat-grid sections (routing + X cvt + W1 transpose;
// W2 transpose runs as tail blocks of gemm1, overlapped with compute)
#define RBLKS  64                      // routing: 256 tokens per block
#define XBLKS  768                     // X cvt: 8 units of 2048 elems each
#define WBLKS  1152                    // W1 transpose: 2 tiles of 64x64 each (rebalanced R15)
#define PREP_BLKS (RBLKS + XBLKS + WBLKS)   // 1984
#define W2BLKS 1152                    // W2 transpose tail blocks inside gemm1 (2 tiles each)

typedef short bf16x8 __attribute__((ext_vector_type(8)));
typedef float f32x4  __attribute__((ext_vector_type(4)));

// ---------------- workspace layout (bytes) ----------------
#define WS_CNT    0u
#define WS_BASES  256u                        // (unused slot, kept for layout stability)
#define WS_POS    512u                        // NTOK ints            = 65536
#define WS_LIST   (512u + 65536u)             // NEXP*NTOK ints       = 262144
#define WS_XB     (WS_LIST + 262144u)         // NTOK*DM bf16         = 25165824
#define WS_W1T    (WS_XB + 25165824u)         // 4*DF*DM bf16         = 18874368
#define WS_W2T    (WS_W1T + 18874368u)        // 4*DM*DF bf16         = 18874368
#define WS_H1     (WS_W2T + 18874368u)        // NTOK*DF bf16         = 100663296
#define WS_H2     (WS_H1 + 100663296u)        // NTOK*DM bf16         = 25165824
#define WS_END    (WS_H2 + 25165824u)

// ---------------- bf16 helpers (manual, RNE) ----------------
__device__ __forceinline__ ushort f2bf(float f) {
    unsigned int v; __builtin_memcpy(&v, &f, 4);
    v = v + 0x7fffu + ((v >> 16) & 1u);
    return (ushort)(v >> 16);
}
__device__ __forceinline__ float bf2f(ushort u) {
    unsigned int v = ((unsigned int)u) << 16;
    float f; __builtin_memcpy(&f, &v, 4); return f;
}

// fast gelu: x * sigmoid(1.5957691(x + 0.044715 x^3)); exp2-based, ~1e-3 abs err
__device__ __forceinline__ float fast_gelu(float v) {
    float y = v + 0.044715f * v * v * v;
    float e = __builtin_amdgcn_exp2f(-2.3022082f * y);
    return v * __builtin_amdgcn_rcpf(1.0f + e);
}

// async global->LDS, 16B per lane. LDS dest must be uniform_base + lane*16.
typedef __attribute__((address_space(1))) const void gvoid_t;
typedef __attribute__((address_space(3))) void lvoid_t;
__device__ __forceinline__ void cp16(const void* g, void* l) {
    __builtin_amdgcn_global_load_lds((gvoid_t*)g, (lvoid_t*)l, 16, 0, 0);
}

// bijective chunked XCD remap over T active blocks (m204 formula)
__device__ __forceinline__ int xcd_remap(int id, int T) {
    const int q = T >> 3, r = T & 7;
    const int x = id & 7, j = id >> 3;
    return (x < r ? x * (q + 1) : r * (q + 1) + (x - r) * q) + j;
}

// ---------------- prep: parallel routing + X cvt + W1 transpose ----------------
__global__ __launch_bounds__(256) void prep_kernel(
    const int* __restrict__ type_seq, const float* __restrict__ X,
    const float* __restrict__ W1,
    int* __restrict__ cnt,
    int* __restrict__ pos_of, int* __restrict__ list,
    ushort* __restrict__ Xb, ushort* __restrict__ W1t) {
    __shared__ ushort tbuf[2][64 * 72];
    __shared__ int lcnt[NEXP];
    __shared__ int lbase[NEXP];
    const int tid = threadIdx.x;
    const int bid = blockIdx.x;

    if (bid < RBLKS) {
        // ---- parallel routing: this block owns tokens [bid*256, bid*256+256) ----
        if (tid < NEXP) lcnt[tid] = 0;
        __syncthreads();
        const int lane = tid & 63;
        const int t = bid * 256 + tid;
        const int k = type_seq[t];
        int my_e = -1, my_p = 0;
#pragma unroll
        for (int e = 0; e < NEXP; ++e) {
            unsigned long long m = __ballot(k == e + 1);
            int total = __popcll(m);
            int b = 0;
            if (lane == 0 && total) b = atomicAdd(&lcnt[e], total);
            b = __shfl(b, 0, 64);
            if (k == e + 1) {
                my_e = e;
                my_p = b + __popcll(m & ((1ull << lane) - 1ull));
            }
        }
        __syncthreads();
        if (tid < NEXP && lcnt[tid] > 0)
            lbase[tid] = atomicAdd(&cnt[tid], lcnt[tid]);   // global, device-scope
        __syncthreads();
        if (my_e >= 0) {
            int gp = lbase[my_e] + my_p;
            list[my_e * NTOK + gp] = t;
            pos_of[t] = gp;
        }
        return;
    }

    int id = bid - RBLKS;
    if (id < XBLKS) {
        // ---- X fp32 -> bf16, 8 batched units per block ----
        size_t ibase = ((size_t)id * 8 * 256 + tid) * 8;
        float4 va[8], vb[8];
#pragma unroll
        for (int k = 0; k < 8; ++k) {
            va[k] = *(const float4*)(X + ibase + (size_t)k * 2048);
            vb[k] = *(const float4*)(X + ibase + (size_t)k * 2048 + 4);
        }
#pragma unroll
        for (int k = 0; k < 8; ++k) {
            ushort tmp[8];
            tmp[0] = f2bf(va[k].x); tmp[1] = f2bf(va[k].y);
            tmp[2] = f2bf(va[k].z); tmp[3] = f2bf(va[k].w);
            tmp[4] = f2bf(vb[k].x); tmp[5] = f2bf(vb[k].y);
            tmp[6] = f2bf(vb[k].z); tmp[7] = f2bf(vb[k].w);
            *(uint4*)(Xb + ibase + (size_t)k * 2048) = *(uint4*)tmp;
        }
        return;
    }
    id -= XBLKS;
    {
        // ---- W1 [z][768][3072] -> W1t [z][3072][768], 2 pipelined tiles ----
        const int lr = tid >> 3;            // 0..31
        const int lc = (tid & 7) * 8;       // 0,8,..,56
        float4 v[2][2];
        const int base_tt = id * 2;
        auto LOADT = [&](int tt) {
            int z = tt / 576, rr = tt % 576, bx = rr % 48, by = rr / 48;
            const float* s0 = W1 + (size_t)z * DM * DF + (size_t)(by * 64 + lr) * DF + bx * 64 + lc;
            v[0][0] = *(const float4*)s0;       v[0][1] = *(const float4*)(s0 + 4);
            const float* s1 = s0 + (size_t)32 * DF;
            v[1][0] = *(const float4*)s1;       v[1][1] = *(const float4*)(s1 + 4);
        };
        LOADT(base_tt);
#pragma unroll 1
        for (int k = 0; k < 2; ++k) {
            ushort* tb = &tbuf[k & 1][0];
#pragma unroll
            for (int q = 0; q < 2; ++q) {
                int r = lr + q * 32;
                ushort tmp[8];
                tmp[0] = f2bf(v[q][0].x); tmp[1] = f2bf(v[q][0].y);
                tmp[2] = f2bf(v[q][0].z); tmp[3] = f2bf(v[q][0].w);
                tmp[4] = f2bf(v[q][1].x); tmp[5] = f2bf(v[q][1].y);
                tmp[6] = f2bf(v[q][1].z); tmp[7] = f2bf(v[q][1].w);
                int sw = (((lc >> 3) ^ ((r >> 3) & 7)) << 3);
                *(uint4*)&tb[r * 72 + sw] = *(uint4*)tmp;
            }
            if (k < 1) LOADT(base_tt + k + 1);
            __syncthreads();
            int tt = base_tt + k;
            int z = tt / 576, rr = tt % 576, bx = rr % 48, by = rr / 48;
#pragma unroll
            for (int q = 0; q < 2; ++q) {
                int r = lr + q * 32;
                ushort tmp[8];
#pragma unroll
                for (int j = 0; j < 8; ++j)
                    tmp[j] = tb[(lc + j) * 72 +
                                ((((r >> 3) & 7) ^ (((lc + j) >> 3) & 7)) << 3) + (r & 7)];
                *(uint4*)(W1t + (size_t)z * DM * DF + (size_t)(bx * 64 + r) * DM + by * 64 + lc) = *(uint4*)tmp;
            }
        }
    }
}

// =====================================================================
// gemm1 (verified R9/R12 best): tile 128x128, 24 n-blocks, 512 thr = 8
// waves of 64x32 output. TRIPLE-buffered LDS (48 KiB, 3 blk/CU), depth-2
// prefetch, counted s_waitcnt vmcnt(2) + raw s_barrier; vmcnt(0) only at
// last iter. sched_barrier(0) pins ordering (rule #18). k-quad XOR
// swizzle (both-sides, conflict-free). XCD remap. Tail blocks (id >= T):
// W2 transpose, 2 tiles each (rebalanced like R15's W1 fix -- 4x tail
// parallelism, shorter serial chain). Inline panel scan.
// =====================================================================
__global__ __launch_bounds__(512, 4) void gemm1_kernel(
    const ushort* __restrict__ Xb, const ushort* __restrict__ W1t,
    const float* __restrict__ b1, const int* __restrict__ cnt,
    const int* __restrict__ list, ushort* __restrict__ h1,
    const float* __restrict__ W2, ushort* __restrict__ W2t) {
    __shared__ __align__(16) short As[3][4096];
    __shared__ __align__(16) short Bs[3][4096];
    const int tid = threadIdx.x;

    const int c0 = cnt[0], c1 = cnt[1], c2 = cnt[2], c3 = cnt[3];
    const int p0 = (c0 + 127) >> 7, p1 = (c1 + 127) >> 7, p2 = (c2 + 127) >> 7;
    const int mb = p0 + p1 + p2 + ((c3 + 127) >> 7);
    const int T = mb * 24;
    int id = blockIdx.y * 24 + blockIdx.x;

    if (id >= T) {
        // ---------- W2 transpose tail blocks: 2 tiles each ----------
        int wid = id - T;
        if (wid >= W2BLKS) return;
        ushort* tb = (ushort*)&As[0][0];        // 9216 B scratch (spans As[0..1])
        const int lr = tid >> 3;                // 0..63
        const int lc = (tid & 7) * 8;           // 0..56
#pragma unroll 1
        for (int k = 0; k < 2; ++k) {
            int tt = wid * 2 + k;
            int zz = tt / 576, rr = tt % 576, bx = rr % 12, by = rr / 12;
            size_t mbase = (size_t)zz * DM * DF;
            const float* s = W2 + mbase + (size_t)(by * 64 + lr) * DM + bx * 64 + lc;
            float4 v0 = *(const float4*)s;
            float4 v1 = *(const float4*)(s + 4);
            ushort tmp[8];
            tmp[0] = f2bf(v0.x); tmp[1] = f2bf(v0.y); tmp[2] = f2bf(v0.z); tmp[3] = f2bf(v0.w);
            tmp[4] = f2bf(v1.x); tmp[5] = f2bf(v1.y); tmp[6] = f2bf(v1.z); tmp[7] = f2bf(v1.w);
            int sw = (((lc >> 3) ^ ((lr >> 3) & 7)) << 3);
            __syncthreads();                    // protect prior iter's reads
            *(uint4*)&tb[lr * 72 + sw] = *(uint4*)tmp;
            __syncthreads();
            ushort o[8];
#pragma unroll
            for (int j = 0; j < 8; ++j)
                o[j] = tb[(lc + j) * 72 +
                          ((((lr >> 3) & 7) ^ (((lc + j) >> 3) & 7)) << 3) + (lr & 7)];
            *(uint4*)(W2t + mbase + (size_t)(bx * 64 + lr) * DF + by * 64 + lc) = *(uint4*)o;
        }
        return;
    }

    id = xcd_remap(id, T);
    const int y = id / 24;
    const int n0 = (id % 24) * 128;
    const int q1 = p0, q2 = p0 + p1, q3 = p0 + p1 + p2;
    const int e = (y >= q1) + (y >= q2) + (y >= q3);
    const int mstart = (e > 0) * p0 + (e > 1) * p1 + (e > 2) * p2;
    const int m0 = (y - mstart) << 7;
    const int count = (e == 0) ? c0 : ((e == 1) ? c1 : ((e == 2) ? c2 : c3));
    const int base = (e > 0) * c0 + (e > 1) * c1 + (e > 2) * c2;
    const int NK = DM / 32;   // 24

    const int wave = tid >> 6, lane = tid & 63;
    const int wm = (wave & 1) * 64, wn = (wave >> 1) * 32;
    const int lrow = lane & 15;
    const int qg = lane >> 4;

    int r0 = min(m0 + (tid >> 2), count - 1);
    int t0 = list[e * NTOK + r0];
    const int qsrc = ((tid & 3) ^ ((tid >> 3) & 3)) * 8;   // source k-quad pre-swizzle
    const ushort* a0 = Xb + (size_t)t0 * DM + qsrc;
    const ushort* Wb = W1t + (size_t)e * DF * DM;
    const ushort* bp0 = Wb + (size_t)(n0 + (tid >> 2)) * DM + qsrc;

    int aOff[4], bOff[2];
#pragma unroll
    for (int i = 0; i < 4; ++i) {
        int ra = wm + i * 16 + lrow;
        aOff[i] = ra * 32 + (qg ^ ((ra >> 1) & 3)) * 8;
    }
#pragma unroll
    for (int j = 0; j < 2; ++j) {
        int rb = wn + j * 16 + lrow;
        bOff[j] = rb * 32 + (qg ^ ((rb >> 1) & 3)) * 8;
    }

    f32x4 z = {0.f, 0.f, 0.f, 0.f};
    f32x4 acc[4][2];
#pragma unroll
    for (int i = 0; i < 4; ++i)
#pragma unroll
        for (int j = 0; j < 2; ++j) acc[i][j] = z;

    auto STAGE = [&](int wb) {
        cp16(a0, &As[0][0] + wb * 4096 + tid * 8);
        cp16(bp0, &Bs[0][0] + wb * 4096 + tid * 8);
        a0 += 32; bp0 += 32;
    };

    STAGE(0); STAGE(1);                         // depth-2 prologue, 4 cp16 in flight
    int rb = 0;
    for (int ks = 0; ks < NK; ++ks) {
        __builtin_amdgcn_sched_barrier(0);
        if (ks + 1 < NK) { asm volatile("s_waitcnt vmcnt(2)" ::: "memory"); }
        else             { asm volatile("s_waitcnt vmcnt(0)" ::: "memory"); }
        __builtin_amdgcn_s_barrier();
        __builtin_amdgcn_sched_barrier(0);
        if (ks + 2 < NK) {
            int wb = rb - 1; if (wb < 0) wb += 3;   // (ks+2)%3
            STAGE(wb);
        }
        const short* Ab = &As[0][0] + rb * 4096;
        const short* Bb = &Bs[0][0] + rb * 4096;
        bf16x8 av[4], bv[2];
#pragma unroll
        for (int i = 0; i < 4; ++i) av[i] = *(const bf16x8*)(Ab + aOff[i]);
#pragma unroll
        for (int j = 0; j < 2; ++j) bv[j] = *(const bf16x8*)(Bb + bOff[j]);
#pragma unroll
        for (int i = 0; i < 4; ++i)
#pragma unroll
            for (int j = 0; j < 2; ++j)
                acc[i][j] = __builtin_amdgcn_mfma_f32_16x16x32_bf16(av[i], bv[j], acc[i][j], 0, 0, 0);
        rb = (rb + 1 == 3) ? 0 : rb + 1;
    }

    float bias[2];
#pragma unroll
    for (int nt = 0; nt < 2; ++nt)
        bias[nt] = b1[e * DF + n0 + wn + nt * 16 + lrow];
#pragma unroll
    for (int mt = 0; mt < 4; ++mt) {
        int gm = m0 + wm + mt * 16 + (lane >> 4) * 4;
#pragma unroll
        for (int nt = 0; nt < 2; ++nt) {
            int gn = n0 + wn + nt * 16 + lrow;
#pragma unroll
            for (int r = 0; r < 4; ++r) {
                int i = gm + r;
                if (i < count) {
                    float v = acc[mt][nt][r] + bias[nt];
                    h1[(size_t)(base + i) * DF + gn] = f2bf(fast_gelu(v));
                }
            }
        }
    }
}

// =====================================================================
// gemm2 (verified config): tile 128x128, 4 waves (2Mx2N) of 64x64,
// BK=32, triple-buffer depth-2 counted vmcnt(4). Inline panel scan.
// 618 blocks fit 3/CU in a single round.
// =====================================================================
__global__ __launch_bounds__(256, 3) void gemm2_kernel(
    const ushort* __restrict__ h1, const ushort* __restrict__ W2t,
    const float* __restrict__ b2, const int* __restrict__ cnt,
    ushort* __restrict__ h2) {
    const int c0 = cnt[0], c1 = cnt[1], c2 = cnt[2], c3 = cnt[3];
    const int p0 = (c0 + 127) >> 7, p1 = (c1 + 127) >> 7, p2 = (c2 + 127) >> 7;
    const int mb = p0 + p1 + p2 + ((c3 + 127) >> 7);
    const int T = mb * 6;
    int id = blockIdx.y * 6 + blockIdx.x;
    if (id >= T) return;
    id = xcd_remap(id, T);
    const int y = id / 6;
    const int n0 = (id % 6) * 128;
    const int q1 = p0, q2 = p0 + p1, q3 = p0 + p1 + p2;
    const int e = (y >= q1) + (y >= q2) + (y >= q3);
    const int mstart = (e > 0) * p0 + (e > 1) * p1 + (e > 2) * p2;
    const int m0 = (y - mstart) << 7;
    const int count = (e == 0) ? c0 : ((e == 1) ? c1 : ((e == 2) ? c2 : c3));
    const int base = (e > 0) * c0 + (e > 1) * c1 + (e > 2) * c2;
    const int NK = DF / 32;   // 96

    __shared__ __align__(16) short As[3][4096];
    __shared__ __align__(16) short Bs[3][4096];

    const int tid = threadIdx.x;
    const int wave = tid >> 6, lane = tid & 63;
    const int wm = (wave & 1) * 64, wn = (wave >> 1) * 64;
    const int lrow = lane & 15;
    const int qg = lane >> 4;

    const int srow = tid >> 2;                              // 0..63
    const int qsrc = ((tid & 3) ^ ((tid >> 3) & 3)) * 8;
    int r0 = min(m0 + srow, count - 1);
    int r1 = min(m0 + 64 + srow, count - 1);
    const ushort* a0 = h1 + (size_t)(base + r0) * DF + qsrc;
    const ushort* a1 = h1 + (size_t)(base + r1) * DF + qsrc;
    const ushort* Wb = W2t + (size_t)e * DM * DF;
    const ushort* bp0 = Wb + (size_t)(n0 + srow) * DF + qsrc;
    const ushort* bp1 = bp0 + (size_t)64 * DF;

    int aOff[4], bOff[4];
#pragma unroll
    for (int i = 0; i < 4; ++i) {
        int ra = wm + i * 16 + lrow;
        aOff[i] = ra * 32 + (qg ^ ((ra >> 1) & 3)) * 8;
        int rbo = wn + i * 16 + lrow;
        bOff[i] = rbo * 32 + (qg ^ ((rbo >> 1) & 3)) * 8;
    }

    f32x4 z = {0.f, 0.f, 0.f, 0.f};
    f32x4 acc[4][4];
#pragma unroll
    for (int i = 0; i < 4; ++i)
#pragma unroll
        for (int j = 0; j < 4; ++j) acc[i][j] = z;

    auto STAGE = [&](int wb) {
        cp16(a0, &As[wb][0] + tid * 8);
        cp16(a1, &As[wb][2048] + tid * 8);
        cp16(bp0, &Bs[wb][0] + tid * 8);
        cp16(bp1, &Bs[wb][2048] + tid * 8);
        a0 += 32; a1 += 32; bp0 += 32; bp1 += 32;
    };

    STAGE(0); STAGE(1);                         // depth-2 prologue, 8 cp16 in flight
    int rb = 0;
    for (int ks = 0; ks < NK; ++ks) {
        __builtin_amdgcn_sched_barrier(0);
        if (ks + 1 < NK) { asm volatile("s_waitcnt vmcnt(4)" ::: "memory"); }
        else             { asm volatile("s_waitcnt vmcnt(0)" ::: "memory"); }
        __builtin_amdgcn_s_barrier();
        __builtin_amdgcn_sched_barrier(0);
        if (ks + 2 < NK) {
            int wb = rb - 1; if (wb < 0) wb += 3;
            STAGE(wb);
        }
        const short* Ab = &As[rb][0];
        const short* Bb = &Bs[rb][0];
        bf16x8 av[4], bv[4];
#pragma unroll
        for (int i = 0; i < 4; ++i) av[i] = *(const bf16x8*)(Ab + aOff[i]);
#pragma unroll
        for (int j = 0; j < 4; ++j) bv[j] = *(const bf16x8*)(Bb + bOff[j]);
#pragma unroll
        for (int i = 0; i < 4; ++i)
#pragma unroll
            for (int j = 0; j < 4; ++j)
                acc[i][j] = __builtin_amdgcn_mfma_f32_16x16x32_bf16(av[i], bv[j], acc[i][j], 0, 0, 0);
        rb = (rb + 1 == 3) ? 0 : rb + 1;
    }

    float bias[4];
#pragma unroll
    for (int j = 0; j < 4; ++j)
        bias[j] = b2[e * DM + n0 + wn + j * 16 + lrow];
#pragma unroll
    for (int i = 0; i < 4; ++i) {
        int gm = m0 + wm + i * 16 + qg * 4;
#pragma unroll
        for (int j = 0; j < 4; ++j) {
            int gn = n0 + wn + j * 16 + lrow;
#pragma unroll
            for (int r = 0; r < 4; ++r) {
                int row = gm + r;
                if (row < count)
                    h2[(size_t)(base + row) * DM + gn] = f2bf(acc[i][j][r] + bias[j]);
            }
        }
    }
}

// ---------------- finalize: 16 tokens/block, one WAVE per 4 tokens ----------------
__global__ __launch_bounds__(256) void finalize_kernel(
    const float* __restrict__ X, const int* __restrict__ type_seq,
    const int* __restrict__ pos_of, const int* __restrict__ cnt,
    const ushort* __restrict__ h2,
    const float* __restrict__ ln_g, const float* __restrict__ ln_b,
    const float* __restrict__ out_g, const float* __restrict__ out_b,
    float* __restrict__ out) {
    const int tid = threadIdx.x;
    const int wave = tid >> 6, lane = tid & 63;
    const int col0 = lane * 4;
    const int c0 = cnt[0], c1 = cnt[1], c2 = cnt[2];

#pragma unroll 1
    for (int ti = 0; ti < 4; ++ti) {
        const int t = blockIdx.x * 16 + wave * 4 + ti;
        const int k = type_seq[t];

        const float* Xr = X + (size_t)t * DM;
        float4 xv[3];
#pragma unroll
        for (int j = 0; j < 3; ++j) xv[j] = *(const float4*)(Xr + col0 + j * 256);

        float rv[12];
        if (k > 0) {
            const int e = k - 1;
            const int base = (e > 0) * c0 + (e > 1) * c1 + (e > 2) * c2;
            const size_t row = (size_t)(base + pos_of[t]);
            const ushort* hr = h2 + row * DM;
            float v[12];
            float s1 = 0.f, s2 = 0.f;
#pragma unroll
            for (int j = 0; j < 3; ++j) {
                ushort4 hv = *(const ushort4*)(hr + col0 + j * 256);
                float f0 = bf2f(hv.x) + xv[j].x;
                float f1 = bf2f(hv.y) + xv[j].y;
                float f2 = bf2f(hv.z) + xv[j].z;
                float f3 = bf2f(hv.w) + xv[j].w;
                v[j * 4 + 0] = f0; v[j * 4 + 1] = f1;
                v[j * 4 + 2] = f2; v[j * 4 + 3] = f3;
                s1 += (f0 + f1) + (f2 + f3);
                s2 += (f0 * f0 + f1 * f1) + (f2 * f2 + f3 * f3);
            }
#pragma unroll
            for (int off = 32; off > 0; off >>= 1) {
                s1 += __shfl_xor(s1, off, 64);
                s2 += __shfl_xor(s2, off, 64);
            }
            float m = s1 * (1.f / DM);
            float inv = rsqrtf(s2 * (1.f / DM) - m * m + 1e-12f);
#pragma unroll
            for (int j = 0; j < 3; ++j) {
                float4 g = *(const float4*)(ln_g + e * DM + col0 + j * 256);
                float4 b = *(const float4*)(ln_b + e * DM + col0 + j * 256);
                rv[j * 4 + 0] = (v[j * 4 + 0] - m) * inv * g.x + b.x;
                rv[j * 4 + 1] = (v[j * 4 + 1] - m) * inv * g.y + b.y;
                rv[j * 4 + 2] = (v[j * 4 + 2] - m) * inv * g.z + b.z;
                rv[j * 4 + 3] = (v[j * 4 + 3] - m) * inv * g.w + b.w;
            }
        } else {
#pragma unroll
            for (int j = 0; j < 12; ++j) rv[j] = 0.f;
        }

        float w[12];
        float s1 = 0.f, s2 = 0.f;
#pragma unroll
        for (int j = 0; j < 3; ++j) {
            float f0 = rv[j * 4 + 0] + xv[j].x;
            float f1 = rv[j * 4 + 1] + xv[j].y;
            float f2 = rv[j * 4 + 2] + xv[j].z;
            float f3 = rv[j * 4 + 3] + xv[j].w;
            w[j * 4 + 0] = f0; w[j * 4 + 1] = f1;
            w[j * 4 + 2] = f2; w[j * 4 + 3] = f3;
            s1 += (f0 + f1) + (f2 + f3);
            s2 += (f0 * f0 + f1 * f1) + (f2 * f2 + f3 * f3);
        }
#pragma unroll
        for (int off = 32; off > 0; off >>= 1) {
            s1 += __shfl_xor(s1, off, 64);
            s2 += __shfl_xor(s2, off, 64);
        }
        float m = s1 * (1.f / DM);
        float inv = rsqrtf(s2 * (1.f / DM) - m * m + 1e-12f);
#pragma unroll
        for (int j = 0; j < 3; ++j) {
            float4 g = *(const float4*)(out_g + col0 + j * 256);
            float4 b = *(const float4*)(out_b + col0 + j * 256);
            float4 o;
            o.x = (w[j * 4 + 0] - m) * inv * g.x + b.x;
            o.y = (w[j * 4 + 1] - m) * inv * g.y + b.y;
            o.z = (w[j * 4 + 2] - m) * inv * g.z + b.z;
            o.w = (w[j * 4 + 3] - m) * inv * g.w + b.w;
            *(float4*)(out + (size_t)t * DM + col0 + j * 256) = o;
        }
    }
}

// ---------------- launcher ----------------
extern "C" void kernel_launch(void* const* d_in, const int* in_sizes, int n_in,
                              void* d_out, int out_size, void* d_ws, size_t ws_size,
                              hipStream_t stream) {
    if (ws_size < (size_t)WS_END) return;

    const float* X     = (const float*)d_in[0];
    const int*   type  = (const int*)d_in[1];
    const float* W1    = (const float*)d_in[2];
    const float* b1    = (const float*)d_in[3];
    const float* W2    = (const float*)d_in[4];
    const float* b2    = (const float*)d_in[5];
    const float* ln_g  = (const float*)d_in[6];
    const float* ln_b  = (const float*)d_in[7];
    const float* out_g = (const float*)d_in[8];
    const float* out_b = (const float*)d_in[9];
    float* out = (float*)d_out;

    char* ws = (char*)d_ws;
    int* cnt    = (int*)(ws + WS_CNT);
    int* pos_of = (int*)(ws + WS_POS);
    int* list   = (int*)(ws + WS_LIST);
    ushort* Xb  = (ushort*)(ws + WS_XB);
    ushort* W1t = (ushort*)(ws + WS_W1T);
    ushort* W2t = (ushort*)(ws + WS_W2T);
    ushort* h1  = (ushort*)(ws + WS_H1);
    ushort* h2  = (ushort*)(ws + WS_H2);

    hipMemsetAsync(cnt, 0, NEXP * sizeof(int), stream);   // routing counters
    prep_kernel<<<PREP_BLKS, 256, 0, stream>>>(type, X, W1,
                                               cnt, pos_of, list, Xb, W1t);
    // gemm1 grid: up to 24*mb active tiles (mb<=132 -> T<=3168) + 1152 W2-tail = 4320
    gemm1_kernel<<<dim3(24, 180), 512, 0, stream>>>(Xb, W1t, b1, cnt, list, h1, W2, W2t);
    gemm2_kernel<<<dim3(6, 132), 256, 0, stream>>>(h1, W2t, b2, cnt, h2);
    finalize_kernel<<<NTOK / 16, 256, 0, stream>>>(X, type, pos_of, cnt, h2, ln_g, ln_b, out_g, out_b, out);
}